// Round 2
// baseline (943.344 us; speedup 1.0000x reference)
//
#include <hip/hip_runtime.h>

#define NN 100000
#define NE 1600000
#define DF 128
#define NG 512
#define NC 10

__global__ void k_zero(int* p, int n){ int i=blockIdx.x*256+threadIdx.x; if(i<n) p[i]=0; }

__global__ void k_count(const int* __restrict__ idx, int* __restrict__ cnt, int n){
  int i=blockIdx.x*256+threadIdx.x; if(i<n) atomicAdd(&cnt[idx[i]],1);
}

__global__ void k_dinv(const int* __restrict__ cnt, float* __restrict__ dinv, int n){
  int i=blockIdx.x*256+threadIdx.x; if(i<n) dinv[i]=rsqrtf((float)cnt[i]+1.0f);
}

__device__ __forceinline__ int block_scan_excl_dev(int v, int* total){
  __shared__ int wsum[33];
  int tid=threadIdx.x, lane=tid&63, wid=tid>>6, nw=(int)(blockDim.x>>6);
  int x=v;
  #pragma unroll
  for(int off=1; off<64; off<<=1){ int t=__shfl_up(x,off,64); if(lane>=off) x+=t; }
  if(lane==63) wsum[wid]=x;
  __syncthreads();
  if(tid==0){ int acc=0; for(int w=0;w<nw;++w){ int t=wsum[w]; wsum[w]=acc; acc+=t; } wsum[32]=acc; }
  __syncthreads();
  if(total) *total=wsum[32];
  return x - v + wsum[wid];
}

__global__ void k_scan1(const int* __restrict__ in, int* __restrict__ out, int* __restrict__ bsum, int n){
  int i=blockIdx.x*1024+threadIdx.x;
  int v=(i<n)? in[i] : 0;
  int total;
  int e=block_scan_excl_dev(v,&total);
  if(i<n) out[i]=e;
  if(threadIdx.x==0) bsum[blockIdx.x]=total;
}

__global__ void k_scan2(const int* __restrict__ bsum, int* __restrict__ bscan, int nb){
  int v=(threadIdx.x<(unsigned)nb)? bsum[threadIdx.x] : 0;
  int e=block_scan_excl_dev(v,nullptr);
  if(threadIdx.x<(unsigned)nb) bscan[threadIdx.x]=e;
}

__global__ void k_scan3(const int* __restrict__ cnt, int* __restrict__ offs, int* __restrict__ pos,
                        const int* __restrict__ bscan, int n){
  int i=blockIdx.x*1024+threadIdx.x;
  if(i<n){
    int o=offs[i]+bscan[blockIdx.x];
    offs[i]=o; pos[i]=o;
    if(i==n-1) offs[n]=o+cnt[i];
  }
}

__global__ void k_gscan(const int* __restrict__ gcnt, int* __restrict__ goff, int n){
  int v=(threadIdx.x<(unsigned)n)? gcnt[threadIdx.x] : 0;
  int tot;
  int e=block_scan_excl_dev(v,&tot);
  if(threadIdx.x<(unsigned)n) goff[threadIdx.x]=e;
  if(threadIdx.x==0) goff[n]=tot;
}

__global__ void k_scatter(const int* __restrict__ src, const int* __restrict__ dst,
                          int* __restrict__ pos, int* __restrict__ csr, int n){
  int i=blockIdx.x*256+threadIdx.x;
  if(i<n){ int p=atomicAdd(&pos[dst[i]],1); csr[p]=src[i]; }
}

// out[row][c] = dinv[row] * sum_k A[row][k]*W[k][c]   (all fp32)
__global__ __launch_bounds__(512) void k_gemm(const float* __restrict__ A, const float* __restrict__ W,
                                              const float* __restrict__ dinv, float* __restrict__ outp, int n){
  __shared__ float sA[128][132];   // 67.6 KB
  __shared__ float sB[128*128];    // 64 KB  (131.6 KB total, fits 160 KB/CU)
  int tid=threadIdx.x;
  int row0=blockIdx.x*128;
  // stage W: 4096 float4
  const float4* W4=(const float4*)W;
  #pragma unroll
  for(int j=0;j<8;++j){
    int c=tid+j*512;
    *(float4*)&sB[c*4]=W4[c];
  }
  // stage A: 128 rows x 32 float4
  const float4* A4=(const float4*)A;
  #pragma unroll
  for(int j=0;j<8;++j){
    int f=tid+j*512;
    int r=f>>5, c4=f&31;
    int row=row0+r;
    float4 v = (row<n)? A4[(size_t)row*32+c4] : make_float4(0.f,0.f,0.f,0.f);
    *(float4*)&sA[r][c4*4]=v;
  }
  __syncthreads();
  int tx=tid&15, ty=tid>>4;      // ty in [0,32)
  int ra=ty*4;
  float acc[4][8];
  #pragma unroll
  for(int r=0;r<4;++r)
    #pragma unroll
    for(int c=0;c<8;++c) acc[r][c]=0.f;
  for(int k=0;k<128;++k){
    float a0=sA[ra+0][k], a1=sA[ra+1][k], a2=sA[ra+2][k], a3=sA[ra+3][k];
    float4 b0=*(float4*)&sB[k*128+tx*8];
    float4 b1=*(float4*)&sB[k*128+tx*8+4];
    float bb[8]={b0.x,b0.y,b0.z,b0.w,b1.x,b1.y,b1.z,b1.w};
    #pragma unroll
    for(int c=0;c<8;++c){
      acc[0][c]=fmaf(a0,bb[c],acc[0][c]);
      acc[1][c]=fmaf(a1,bb[c],acc[1][c]);
      acc[2][c]=fmaf(a2,bb[c],acc[2][c]);
      acc[3][c]=fmaf(a3,bb[c],acc[3][c]);
    }
  }
  #pragma unroll
  for(int r=0;r<4;++r){
    int row=row0+ra+r;
    if(row<n){
      float di=dinv[row];
      float4 o0={acc[r][0]*di,acc[r][1]*di,acc[r][2]*di,acc[r][3]*di};
      float4 o1={acc[r][4]*di,acc[r][5]*di,acc[r][6]*di,acc[r][7]*di};
      float4* op=(float4*)&outp[(size_t)row*128+tx*8];
      op[0]=o0; op[1]=o1;
    }
  }
}

// out[i] = relu(dinv[i]*(h2[i] + sum_{e in CSR[i]} h2[csr[e]]) + b)
__global__ __launch_bounds__(256) void k_agg(const float* __restrict__ h2, const int* __restrict__ offs,
                                             const int* __restrict__ csr, const float* __restrict__ dinv,
                                             const float* __restrict__ bias, float* __restrict__ outp, int n){
  int wid=threadIdx.x>>6, lane=threadIdx.x&63;
  int node=blockIdx.x*4+wid;
  if(node>=n) return;
  const float2* h2v=(const float2*)h2;
  float2 acc=h2v[(size_t)node*64+lane];
  int e0=offs[node], e1=offs[node+1];
  int e=e0;
  for(; e+1<e1; e+=2){
    int s0=csr[e], s1=csr[e+1];
    float2 v0=h2v[(size_t)s0*64+lane];
    float2 v1=h2v[(size_t)s1*64+lane];
    acc.x+=v0.x+v1.x; acc.y+=v0.y+v1.y;
  }
  if(e<e1){
    int s=csr[e];
    float2 v=h2v[(size_t)s*64+lane];
    acc.x+=v.x; acc.y+=v.y;
  }
  float di=dinv[node];
  float2 b=*(const float2*)&bias[lane*2];
  float ox=fmaf(di,acc.x,b.x), oy=fmaf(di,acc.y,b.y);
  ox=ox>0.f?ox:0.f; oy=oy>0.f?oy:0.f;
  ((float2*)outp)[(size_t)node*64+lane]=make_float2(ox,oy);
}

// pooled[g] = mean of h rows in [goff[g],goff[g+1]); out = pooled@Wc + bc
__global__ __launch_bounds__(128) void k_pool(const float* __restrict__ h, const int* __restrict__ goff,
                                              const float* __restrict__ Wc, const float* __restrict__ bc,
                                              float* __restrict__ outp){
  __shared__ float lds[128];
  int g=blockIdx.x, d=threadIdx.x;
  int i0=goff[g], i1=goff[g+1];
  float acc=0.f;
  for(int i=i0;i<i1;++i) acc+=h[(size_t)i*128+d];
  int cnt=i1-i0;
  float p=(cnt>0)? acc/(float)cnt : 0.f;
  lds[d]=p;
  __syncthreads();
  if(d<NC){
    float s=bc[d];
    for(int k=0;k<128;++k) s=fmaf(lds[k], Wc[k*NC+d], s);
    outp[g*NC+d]=s;
  }
}

extern "C" void kernel_launch(void* const* d_in, const int* in_sizes, int n_in,
                              void* d_out, int out_size, void* d_ws, size_t ws_size,
                              hipStream_t stream){
  const float* x   =(const float*)d_in[0];
  const int* esrc  =(const int*)d_in[1];
  const int* edst  =(const int*)d_in[2];
  const int* batch =(const int*)d_in[3];
  const float* W0=(const float*)d_in[4];  const float* b0=(const float*)d_in[5];
  const float* W1=(const float*)d_in[6];  const float* b1=(const float*)d_in[7];
  const float* W2=(const float*)d_in[8];  const float* b2=(const float*)d_in[9];
  const float* Wc=(const float*)d_in[10]; const float* bc=(const float*)d_in[11];
  float* out=(float*)d_out;

  char* base=(char*)d_ws; size_t off=0;
  auto alloc=[&](size_t bytes)->void*{ off=(off+255)&~(size_t)255; void* p=base+off; off+=bytes; return p; };
  int*   cnt  =(int*)  alloc((size_t)NN*4);
  int*   offs =(int*)  alloc((size_t)(NN+1)*4);
  int*   pos  =(int*)  alloc((size_t)NN*4);
  int*   bsum =(int*)  alloc(128*4);
  int*   bscan=(int*)  alloc(128*4);
  int*   gcnt =(int*)  alloc(NG*4);
  int*   goff =(int*)  alloc((NG+1)*4);
  float* dinv =(float*)alloc((size_t)NN*4);
  int*   csr  =(int*)  alloc((size_t)NE*4);
  float* bufA =(float*)alloc((size_t)NN*DF*4);
  float* bufB =(float*)alloc((size_t)NN*DF*4);
  (void)ws_size; (void)in_sizes; (void)n_in; (void)out_size;

  const int NB_E=(NE+255)/256, NB_N=(NN+255)/256, NB_S=(NN+1023)/1024;

  hipLaunchKernelGGL(k_zero,   dim3(NB_N), dim3(256), 0, stream, cnt, NN);
  hipLaunchKernelGGL(k_zero,   dim3(2),    dim3(256), 0, stream, gcnt, NG);
  hipLaunchKernelGGL(k_count,  dim3(NB_E), dim3(256), 0, stream, edst, cnt, NE);
  hipLaunchKernelGGL(k_count,  dim3(NB_N), dim3(256), 0, stream, batch, gcnt, NN);
  hipLaunchKernelGGL(k_dinv,   dim3(NB_N), dim3(256), 0, stream, cnt, dinv, NN);
  hipLaunchKernelGGL(k_scan1,  dim3(NB_S), dim3(1024),0, stream, cnt, offs, bsum, NN);
  hipLaunchKernelGGL(k_scan2,  dim3(1),    dim3(128), 0, stream, bsum, bscan, NB_S);
  hipLaunchKernelGGL(k_scan3,  dim3(NB_S), dim3(1024),0, stream, cnt, offs, pos, bscan, NN);
  hipLaunchKernelGGL(k_gscan,  dim3(1),    dim3(512), 0, stream, gcnt, goff, NG);
  hipLaunchKernelGGL(k_scatter,dim3(NB_E), dim3(256), 0, stream, esrc, edst, pos, csr, NE);

  const int GB=(NN+127)/128;    // 782
  const int AB=(NN+3)/4;        // 25000

  hipLaunchKernelGGL(k_gemm, dim3(GB), dim3(512), 0, stream, x,    W0, dinv, bufA, NN);
  hipLaunchKernelGGL(k_agg,  dim3(AB), dim3(256), 0, stream, bufA, offs, csr, dinv, b0, bufB, NN);
  hipLaunchKernelGGL(k_gemm, dim3(GB), dim3(512), 0, stream, bufB, W1, dinv, bufA, NN);
  hipLaunchKernelGGL(k_agg,  dim3(AB), dim3(256), 0, stream, bufA, offs, csr, dinv, b1, bufB, NN);
  hipLaunchKernelGGL(k_gemm, dim3(GB), dim3(512), 0, stream, bufB, W2, dinv, bufA, NN);
  hipLaunchKernelGGL(k_agg,  dim3(AB), dim3(256), 0, stream, bufA, offs, csr, dinv, b2, bufB, NN);
  hipLaunchKernelGGL(k_pool, dim3(NG), dim3(128), 0, stream, bufB, goff, Wc, bc, out);
}

// Round 3
// 703.803 us; speedup vs baseline: 1.3404x; 1.3404x over previous
//
#include <hip/hip_runtime.h>

#define NN 100000
#define NE 1600000
#define DF 128
#define NG 512
#define NC 10

typedef unsigned short u16;
typedef unsigned int u32;
typedef __bf16 bf16_t;
typedef bf16_t bf16x8 __attribute__((ext_vector_type(8)));
typedef float f32x4 __attribute__((ext_vector_type(4)));

__device__ __forceinline__ u16 f2bf(float f){
  u32 x=__float_as_uint(f);
  u32 r=(x+0x7fffu+((x>>16)&1u))>>16;
  return (u16)r;
}
__device__ __forceinline__ float bflo(u32 u){ return __uint_as_float(u<<16); }
__device__ __forceinline__ float bfhi(u32 u){ return __uint_as_float(u&0xffff0000u); }

__global__ void k_zero(int* p, int n){ int i=blockIdx.x*256+threadIdx.x; if(i<n) p[i]=0; }

__global__ void k_count(const int* __restrict__ idx, int* __restrict__ cnt, int n){
  int i=blockIdx.x*256+threadIdx.x; if(i<n) atomicAdd(&cnt[idx[i]],1);
}

__global__ void k_dinv(const int* __restrict__ cnt, float* __restrict__ dinv, int n){
  int i=blockIdx.x*256+threadIdx.x; if(i<n) dinv[i]=rsqrtf((float)cnt[i]+1.0f);
}

__device__ __forceinline__ int block_scan_excl_dev(int v, int* total){
  __shared__ int wsum[33];
  int tid=threadIdx.x, lane=tid&63, wid=tid>>6, nw=(int)(blockDim.x>>6);
  int x=v;
  #pragma unroll
  for(int off=1; off<64; off<<=1){ int t=__shfl_up(x,off,64); if(lane>=off) x+=t; }
  if(lane==63) wsum[wid]=x;
  __syncthreads();
  if(tid==0){ int acc=0; for(int w=0;w<nw;++w){ int t=wsum[w]; wsum[w]=acc; acc+=t; } wsum[32]=acc; }
  __syncthreads();
  if(total) *total=wsum[32];
  return x - v + wsum[wid];
}

__global__ void k_scan1(const int* __restrict__ in, int* __restrict__ out, int* __restrict__ bsum, int n){
  int i=blockIdx.x*1024+threadIdx.x;
  int v=(i<n)? in[i] : 0;
  int total;
  int e=block_scan_excl_dev(v,&total);
  if(i<n) out[i]=e;
  if(threadIdx.x==0) bsum[blockIdx.x]=total;
}

__global__ void k_scan2(const int* __restrict__ bsum, int* __restrict__ bscan, int nb){
  int v=(threadIdx.x<(unsigned)nb)? bsum[threadIdx.x] : 0;
  int e=block_scan_excl_dev(v,nullptr);
  if(threadIdx.x<(unsigned)nb) bscan[threadIdx.x]=e;
}

__global__ void k_scan3(const int* __restrict__ cnt, int* __restrict__ offs, int* __restrict__ pos,
                        const int* __restrict__ bscan, int n){
  int i=blockIdx.x*1024+threadIdx.x;
  if(i<n){
    int o=offs[i]+bscan[blockIdx.x];
    offs[i]=o; pos[i]=o;
    if(i==n-1) offs[n]=o+cnt[i];
  }
}

__global__ void k_gscan(const int* __restrict__ gcnt, int* __restrict__ goff, int n){
  int v=(threadIdx.x<(unsigned)n)? gcnt[threadIdx.x] : 0;
  int tot;
  int e=block_scan_excl_dev(v,&tot);
  if(threadIdx.x<(unsigned)n) goff[threadIdx.x]=e;
  if(threadIdx.x==0) goff[n]=tot;
}

__global__ void k_scatter(const int* __restrict__ src, const int* __restrict__ dst,
                          int* __restrict__ pos, int* __restrict__ csr, int n){
  int i=blockIdx.x*256+threadIdx.x;
  if(i<n){ int p=atomicAdd(&pos[dst[i]],1); csr[p]=src[i]; }
}

// W fp32 [128][128] row-major -> WT bf16 [n][k]
__global__ void k_prepW(const float* __restrict__ W, u16* __restrict__ WT){
  int t=blockIdx.x*256+threadIdx.x;
  if(t<DF*DF){ int k=t>>7, n=t&127; WT[n*128+k]=f2bf(W[t]); }
}

// out[row][c] = bf16( dinv[row] * sum_k A[row][k]*W[k][c] ), MFMA bf16
template<bool F32IN>
__global__ __launch_bounds__(256) void k_gemm(const void* __restrict__ Ap, const u16* __restrict__ WT,
                                              const float* __restrict__ dinv, u16* __restrict__ outp, int n){
  __shared__ u16 sA[128][136];   // 34.8 KB, row stride 272B (4-bank shift/row -> 2-way = free)
  __shared__ u16 sW[128][136];   // W^T: sW[n][k]
  int tid=threadIdx.x;
  int row0=blockIdx.x*128;
  {
    const uint4* p=(const uint4*)WT;
    #pragma unroll
    for(int j=0;j<8;++j){
      int c=tid+j*256;             // 2048 chunks of 8 bf16
      int r=c>>4, c8=c&15;
      *(uint4*)&sA[0][0] ; // no-op to keep structure clear
      *(uint4*)&sW[r][c8*8]=p[c];
    }
  }
  if(F32IN){
    const float4* A4=(const float4*)Ap;
    #pragma unroll
    for(int j=0;j<16;++j){
      int c=tid+j*256;             // 4096 chunks of 4 floats
      int r=c>>5, c4=c&31;
      int row=row0+r;
      float4 v = (row<n)? A4[(size_t)row*32+c4] : make_float4(0.f,0.f,0.f,0.f);
      u32 lo=(u32)f2bf(v.x) | ((u32)f2bf(v.y)<<16);
      u32 hi=(u32)f2bf(v.z) | ((u32)f2bf(v.w)<<16);
      uint2 q; q.x=lo; q.y=hi;
      *(uint2*)&sA[r][c4*4]=q;
    }
  } else {
    const uint4* A4=(const uint4*)Ap;
    #pragma unroll
    for(int j=0;j<8;++j){
      int c=tid+j*256;             // 2048 chunks of 8 bf16
      int r=c>>4, c8=c&15;
      int row=row0+r;
      uint4 v = (row<n)? A4[(size_t)row*16+c8] : make_uint4(0,0,0,0);
      *(uint4*)&sA[r][c8*8]=v;
    }
  }
  __syncthreads();
  int wv=tid>>6, lane=tid&63;
  int lr=lane&15, lk=lane>>4;      // lk in 0..3
  f32x4 acc[2][8];
  #pragma unroll
  for(int mr=0;mr<2;++mr)
    #pragma unroll
    for(int nt=0;nt<8;++nt) acc[mr][nt]=(f32x4){0.f,0.f,0.f,0.f};
  #pragma unroll
  for(int kk=0;kk<4;++kk){
    bf16x8 a[2], b[8];
    #pragma unroll
    for(int mr=0;mr<2;++mr)
      a[mr]=*(const bf16x8*)&sA[wv*32+mr*16+lr][kk*32+lk*8];
    #pragma unroll
    for(int nt=0;nt<8;++nt)
      b[nt]=*(const bf16x8*)&sW[nt*16+lr][kk*32+lk*8];
    #pragma unroll
    for(int mr=0;mr<2;++mr)
      #pragma unroll
      for(int nt=0;nt<8;++nt)
        acc[mr][nt]=__builtin_amdgcn_mfma_f32_16x16x32_bf16(a[mr],b[nt],acc[mr][nt],0,0,0);
  }
  #pragma unroll
  for(int mr=0;mr<2;++mr){
    int rbase=row0+wv*32+mr*16+lk*4;
    #pragma unroll
    for(int r=0;r<4;++r){
      int row=rbase+r;
      if(row<n){
        float di=dinv[row];
        #pragma unroll
        for(int nt=0;nt<8;++nt)
          outp[(size_t)row*128+nt*16+lr]=f2bf(acc[mr][nt][r]*di);
      }
    }
  }
}

// out[i] = bf16( relu(dinv[i]*(h2[i] + sum_{e} h2[csr[e]]) + b) ), h2 bf16
__global__ __launch_bounds__(256) void k_agg(const u16* __restrict__ h2, const int* __restrict__ offs,
                                             const int* __restrict__ csr, const float* __restrict__ dinv,
                                             const float* __restrict__ bias, u16* __restrict__ outp, int n){
  int wid=threadIdx.x>>6, lane=threadIdx.x&63;
  int node=blockIdx.x*4+wid;
  if(node>=n) return;
  const u32* hv=(const u32*)h2;
  u32 s=hv[(size_t)node*64+lane];
  float ax=bflo(s), ay=bfhi(s);
  int e0=offs[node], e1=offs[node+1];
  int e=e0;
  for(; e+1<e1; e+=2){
    u32 v0=hv[(size_t)csr[e]*64+lane];
    u32 v1=hv[(size_t)csr[e+1]*64+lane];
    ax+=bflo(v0)+bflo(v1); ay+=bfhi(v0)+bfhi(v1);
  }
  if(e<e1){
    u32 v=hv[(size_t)csr[e]*64+lane];
    ax+=bflo(v); ay+=bfhi(v);
  }
  float di=dinv[node];
  float2 b=*(const float2*)&bias[lane*2];
  float ox=fmaf(di,ax,b.x), oy=fmaf(di,ay,b.y);
  ox=ox>0.f?ox:0.f; oy=oy>0.f?oy:0.f;
  u32 o=(u32)f2bf(ox) | ((u32)f2bf(oy)<<16);
  ((u32*)outp)[(size_t)node*64+lane]=o;
}

// pooled[g] = mean of bf16 h rows in [goff[g],goff[g+1]); out = pooled@Wc + bc (fp32)
__global__ __launch_bounds__(128) void k_pool(const u16* __restrict__ h, const int* __restrict__ goff,
                                              const float* __restrict__ Wc, const float* __restrict__ bc,
                                              float* __restrict__ outp){
  __shared__ float lds[128];
  int g=blockIdx.x, d=threadIdx.x;
  int i0=goff[g], i1=goff[g+1];
  float acc=0.f;
  for(int i=i0;i<i1;++i) acc+=__uint_as_float(((u32)h[(size_t)i*128+d])<<16);
  int cnt=i1-i0;
  float p=(cnt>0)? acc/(float)cnt : 0.f;
  lds[d]=p;
  __syncthreads();
  if(d<NC){
    float s=bc[d];
    for(int k=0;k<128;++k) s=fmaf(lds[k], Wc[k*NC+d], s);
    outp[g*NC+d]=s;
  }
}

extern "C" void kernel_launch(void* const* d_in, const int* in_sizes, int n_in,
                              void* d_out, int out_size, void* d_ws, size_t ws_size,
                              hipStream_t stream){
  const float* x   =(const float*)d_in[0];
  const int* esrc  =(const int*)d_in[1];
  const int* edst  =(const int*)d_in[2];
  const int* batch =(const int*)d_in[3];
  const float* W0=(const float*)d_in[4];  const float* b0=(const float*)d_in[5];
  const float* W1=(const float*)d_in[6];  const float* b1=(const float*)d_in[7];
  const float* W2=(const float*)d_in[8];  const float* b2=(const float*)d_in[9];
  const float* Wc=(const float*)d_in[10]; const float* bc=(const float*)d_in[11];
  float* out=(float*)d_out;

  char* base=(char*)d_ws; size_t off=0;
  auto alloc=[&](size_t bytes)->void*{ off=(off+255)&~(size_t)255; void* p=base+off; off+=bytes; return p; };
  int*   cnt  =(int*)  alloc((size_t)NN*4);
  int*   offs =(int*)  alloc((size_t)(NN+1)*4);
  int*   pos  =(int*)  alloc((size_t)NN*4);
  int*   bsum =(int*)  alloc(128*4);
  int*   bscan=(int*)  alloc(128*4);
  int*   gcnt =(int*)  alloc(NG*4);
  int*   goff =(int*)  alloc((NG+1)*4);
  float* dinv =(float*)alloc((size_t)NN*4);
  int*   csr  =(int*)  alloc((size_t)NE*4);
  u16*   WT0  =(u16*)  alloc((size_t)DF*DF*2);
  u16*   WT1  =(u16*)  alloc((size_t)DF*DF*2);
  u16*   WT2  =(u16*)  alloc((size_t)DF*DF*2);
  u16*   bufA =(u16*)  alloc((size_t)NN*DF*2);
  u16*   bufB =(u16*)  alloc((size_t)NN*DF*2);
  (void)ws_size; (void)in_sizes; (void)n_in; (void)out_size;

  const int NB_E=(NE+255)/256, NB_N=(NN+255)/256, NB_S=(NN+1023)/1024;

  hipLaunchKernelGGL(k_zero,   dim3(NB_N), dim3(256), 0, stream, cnt, NN);
  hipLaunchKernelGGL(k_zero,   dim3(2),    dim3(256), 0, stream, gcnt, NG);
  hipLaunchKernelGGL(k_prepW,  dim3(64),   dim3(256), 0, stream, W0, WT0);
  hipLaunchKernelGGL(k_prepW,  dim3(64),   dim3(256), 0, stream, W1, WT1);
  hipLaunchKernelGGL(k_prepW,  dim3(64),   dim3(256), 0, stream, W2, WT2);
  hipLaunchKernelGGL(k_count,  dim3(NB_E), dim3(256), 0, stream, edst, cnt, NE);
  hipLaunchKernelGGL(k_count,  dim3(NB_N), dim3(256), 0, stream, batch, gcnt, NN);
  hipLaunchKernelGGL(k_dinv,   dim3(NB_N), dim3(256), 0, stream, cnt, dinv, NN);
  hipLaunchKernelGGL(k_scan1,  dim3(NB_S), dim3(1024),0, stream, cnt, offs, bsum, NN);
  hipLaunchKernelGGL(k_scan2,  dim3(1),    dim3(128), 0, stream, bsum, bscan, NB_S);
  hipLaunchKernelGGL(k_scan3,  dim3(NB_S), dim3(1024),0, stream, cnt, offs, pos, bscan, NN);
  hipLaunchKernelGGL(k_gscan,  dim3(1),    dim3(512), 0, stream, gcnt, goff, NG);
  hipLaunchKernelGGL(k_scatter,dim3(NB_E), dim3(256), 0, stream, esrc, edst, pos, csr, NE);

  const int GB=(NN+127)/128;    // 782
  const int AB=(NN+3)/4;        // 25000

  k_gemm<true ><<<dim3(GB), dim3(256), 0, stream>>>((const void*)x,    WT0, dinv, bufA, NN);
  hipLaunchKernelGGL(k_agg,  dim3(AB), dim3(256), 0, stream, bufA, offs, csr, dinv, b0, bufB, NN);
  k_gemm<false><<<dim3(GB), dim3(256), 0, stream>>>((const void*)bufB, WT1, dinv, bufA, NN);
  hipLaunchKernelGGL(k_agg,  dim3(AB), dim3(256), 0, stream, bufA, offs, csr, dinv, b1, bufB, NN);
  k_gemm<false><<<dim3(GB), dim3(256), 0, stream>>>((const void*)bufB, WT2, dinv, bufA, NN);
  hipLaunchKernelGGL(k_agg,  dim3(AB), dim3(256), 0, stream, bufA, offs, csr, dinv, b2, bufB, NN);
  hipLaunchKernelGGL(k_pool, dim3(NG), dim3(128), 0, stream, bufB, goff, Wc, bc, out);
}

// Round 4
// 543.002 us; speedup vs baseline: 1.7373x; 1.2961x over previous
//
#include <hip/hip_runtime.h>

#define NN 100000
#define NE 1600000
#define DF 128
#define NG 512
#define NC 10
#define NBK 8
#define NPB 12500      // nodes per bucket (NN/NBK exact)
#define BKCAP 262144   // pairs capacity per bucket (mean 200K, >>100 sigma margin)
#define PCH 4096       // edges per partition block

typedef unsigned short u16;
typedef unsigned int u32;
typedef __bf16 bf16_t;
typedef bf16_t bf16x8 __attribute__((ext_vector_type(8)));
typedef float f32x4 __attribute__((ext_vector_type(4)));

__device__ __forceinline__ u16 f2bf(float f){
  u32 x=__float_as_uint(f);
  u32 r=(x+0x7fffu+((x>>16)&1u))>>16;
  return (u16)r;
}
__device__ __forceinline__ float bflo(u32 u){ return __uint_as_float(u<<16); }
__device__ __forceinline__ float bfhi(u32 u){ return __uint_as_float(u&0xffff0000u); }

__global__ void k_zero(int* p, int n){ int i=blockIdx.x*256+threadIdx.x; if(i<n) p[i]=0; }

__global__ void k_count(const int* __restrict__ idx, int* __restrict__ cnt, int n){
  int i=blockIdx.x*256+threadIdx.x; if(i<n) atomicAdd(&cnt[idx[i]],1);
}

// partition edges into 8 dst-range buckets; also produce per-node degree counts
__global__ __launch_bounds__(256) void k_part8(const int* __restrict__ esrc, const int* __restrict__ edst,
                                               int* __restrict__ cur, uint2* __restrict__ pairs,
                                               int* __restrict__ cnt, int n){
  __shared__ int hist[NBK], basev[NBK], lcur[NBK];
  int tid=threadIdx.x;
  int start=blockIdx.x*PCH;
  int end=min(start+PCH, n);
  if(tid<NBK) hist[tid]=0;
  __syncthreads();
  for(int i=start+tid;i<end;i+=256){
    int d=edst[i];
    atomicAdd(&cnt[d],1);
    atomicAdd(&hist[(u32)d/NPB],1);
  }
  __syncthreads();
  if(tid<NBK){ basev[tid]=atomicAdd(&cur[tid],hist[tid]); lcur[tid]=0; }
  __syncthreads();
  for(int i=start+tid;i<end;i+=256){
    int d=edst[i], s=esrc[i];
    int b=(u32)d/NPB;
    int p=atomicAdd(&lcur[b],1);
    pairs[(size_t)b*BKCAP + basev[b] + p]=make_uint2((u32)s,(u32)d);
  }
}

// XCD-pinned CSR build: bucket = blockIdx&7
__global__ __launch_bounds__(256) void k_place(const uint2* __restrict__ pairs, const int* __restrict__ cur,
                                               int* __restrict__ pos, int* __restrict__ csr){
  int b=blockIdx.x&7, bi=blockIdx.x>>3, nb=gridDim.x>>3;
  int cnt=cur[b];
  const uint2* P=pairs+(size_t)b*BKCAP;
  for(int i=bi*256+threadIdx.x;i<cnt;i+=nb*256){
    uint2 e=P[i];
    int p=atomicAdd(&pos[e.y],1);
    csr[p]=(int)e.x;
  }
}

__device__ __forceinline__ int block_scan_excl_dev(int v, int* total){
  __shared__ int wsum[33];
  int tid=threadIdx.x, lane=tid&63, wid=tid>>6, nw=(int)(blockDim.x>>6);
  int x=v;
  #pragma unroll
  for(int off=1; off<64; off<<=1){ int t=__shfl_up(x,off,64); if(lane>=off) x+=t; }
  if(lane==63) wsum[wid]=x;
  __syncthreads();
  if(tid==0){ int acc=0; for(int w=0;w<nw;++w){ int t=wsum[w]; wsum[w]=acc; acc+=t; } wsum[32]=acc; }
  __syncthreads();
  if(total) *total=wsum[32];
  return x - v + wsum[wid];
}

__global__ void k_scan1(const int* __restrict__ in, int* __restrict__ out, int* __restrict__ bsum, int n){
  int i=blockIdx.x*1024+threadIdx.x;
  int v=(i<n)? in[i] : 0;
  int total;
  int e=block_scan_excl_dev(v,&total);
  if(i<n) out[i]=e;
  if(threadIdx.x==0) bsum[blockIdx.x]=total;
}

__global__ void k_scan2(const int* __restrict__ bsum, int* __restrict__ bscan, int nb){
  int v=(threadIdx.x<(unsigned)nb)? bsum[threadIdx.x] : 0;
  int e=block_scan_excl_dev(v,nullptr);
  if(threadIdx.x<(unsigned)nb) bscan[threadIdx.x]=e;
}

__global__ void k_scan3(const int* __restrict__ cnt, int* __restrict__ offs, int* __restrict__ pos,
                        const int* __restrict__ bscan, float* __restrict__ dinv, int n){
  int i=blockIdx.x*1024+threadIdx.x;
  if(i<n){
    int o=offs[i]+bscan[blockIdx.x];
    offs[i]=o; pos[i]=o;
    dinv[i]=rsqrtf((float)cnt[i]+1.0f);
    if(i==n-1) offs[n]=o+cnt[i];
  }
}

__global__ void k_gscan(const int* __restrict__ gcnt, int* __restrict__ goff, int n){
  int v=(threadIdx.x<(unsigned)n)? gcnt[threadIdx.x] : 0;
  int tot;
  int e=block_scan_excl_dev(v,&tot);
  if(threadIdx.x<(unsigned)n) goff[threadIdx.x]=e;
  if(threadIdx.x==0) goff[n]=tot;
}

// all three W fp32 [128][128] row-major -> WT bf16 [w][n][k]
__global__ void k_prepW(const float* __restrict__ W0, const float* __restrict__ W1,
                        const float* __restrict__ W2, u16* __restrict__ WT){
  int t=blockIdx.x*256+threadIdx.x;   // grid 192 -> 49152 = 3*16384
  int w=t>>14, r=t&16383;
  const float* W = (w==0)?W0:((w==1)?W1:W2);
  int k=r>>7, n=r&127;
  WT[(size_t)w*DF*DF + n*128+k]=f2bf(W[r]);
}

// out[row][c] = bf16( dinv[row] * sum_k A[row][k]*W[k][c] ), MFMA bf16
template<bool F32IN>
__global__ __launch_bounds__(256) void k_gemm(const void* __restrict__ Ap, const u16* __restrict__ WT,
                                              const float* __restrict__ dinv, u16* __restrict__ outp, int n){
  __shared__ u16 sA[128][136];   // row stride 272B -> 2-way bank alias (free)
  __shared__ u16 sW[128][136];   // W^T: sW[n][k]
  int tid=threadIdx.x;
  int row0=blockIdx.x*128;
  {
    const uint4* p=(const uint4*)WT;
    #pragma unroll
    for(int j=0;j<8;++j){
      int c=tid+j*256;             // 2048 chunks of 8 bf16
      int r=c>>4, c8=c&15;
      *(uint4*)&sW[r][c8*8]=p[c];
    }
  }
  if(F32IN){
    const float4* A4=(const float4*)Ap;
    #pragma unroll
    for(int j=0;j<16;++j){
      int c=tid+j*256;             // 4096 chunks of 4 floats
      int r=c>>5, c4=c&31;
      int row=row0+r;
      float4 v = (row<n)? A4[(size_t)row*32+c4] : make_float4(0.f,0.f,0.f,0.f);
      u32 lo=(u32)f2bf(v.x) | ((u32)f2bf(v.y)<<16);
      u32 hi=(u32)f2bf(v.z) | ((u32)f2bf(v.w)<<16);
      uint2 q; q.x=lo; q.y=hi;
      *(uint2*)&sA[r][c4*4]=q;
    }
  } else {
    const uint4* A4=(const uint4*)Ap;
    #pragma unroll
    for(int j=0;j<8;++j){
      int c=tid+j*256;             // 2048 chunks of 8 bf16
      int r=c>>4, c8=c&15;
      int row=row0+r;
      uint4 v = (row<n)? A4[(size_t)row*16+c8] : make_uint4(0,0,0,0);
      *(uint4*)&sA[r][c8*8]=v;
    }
  }
  __syncthreads();
  int wv=tid>>6, lane=tid&63;
  int lr=lane&15, lk=lane>>4;      // lk in 0..3
  f32x4 acc[2][8];
  #pragma unroll
  for(int mr=0;mr<2;++mr)
    #pragma unroll
    for(int nt=0;nt<8;++nt) acc[mr][nt]=(f32x4){0.f,0.f,0.f,0.f};
  #pragma unroll
  for(int kk=0;kk<4;++kk){
    bf16x8 a[2], b[8];
    #pragma unroll
    for(int mr=0;mr<2;++mr)
      a[mr]=*(const bf16x8*)&sA[wv*32+mr*16+lr][kk*32+lk*8];
    #pragma unroll
    for(int nt=0;nt<8;++nt)
      b[nt]=*(const bf16x8*)&sW[nt*16+lr][kk*32+lk*8];
    #pragma unroll
    for(int mr=0;mr<2;++mr)
      #pragma unroll
      for(int nt=0;nt<8;++nt)
        acc[mr][nt]=__builtin_amdgcn_mfma_f32_16x16x32_bf16(a[mr],b[nt],acc[mr][nt],0,0,0);
  }
  #pragma unroll
  for(int mr=0;mr<2;++mr){
    int rbase=row0+wv*32+mr*16+lk*4;
    #pragma unroll
    for(int r=0;r<4;++r){
      int row=rbase+r;
      if(row<n){
        float di=dinv[row];
        #pragma unroll
        for(int nt=0;nt<8;++nt)
          outp[(size_t)row*128+nt*16+lr]=f2bf(acc[mr][nt][r]*di);
      }
    }
  }
}

// out[i] = bf16( relu(dinv[i]*(h2[i] + sum_e h2[csr[e]]) + b) )
__global__ __launch_bounds__(256) void k_agg(const u16* __restrict__ h2, const int* __restrict__ offs,
                                             const int* __restrict__ csr, const float* __restrict__ dinv,
                                             const float* __restrict__ bias, u16* __restrict__ outp, int n){
  int wid=threadIdx.x>>6, lane=threadIdx.x&63;
  int node=blockIdx.x*4+wid;
  if(node>=n) return;
  const u32* hv=(const u32*)h2;
  u32 sv=hv[(size_t)node*64+lane];
  float ax=bflo(sv), ay=bfhi(sv);
  int e=offs[node], e1=offs[node+1];
  // 8-wide main loop: 8 independent gathers in flight
  for(; e+8<=e1; e+=8){
    int i0=csr[e],i1=csr[e+1],i2=csr[e+2],i3=csr[e+3];
    int i4=csr[e+4],i5=csr[e+5],i6=csr[e+6],i7=csr[e+7];
    u32 v0=hv[(size_t)i0*64+lane], v1=hv[(size_t)i1*64+lane];
    u32 v2=hv[(size_t)i2*64+lane], v3=hv[(size_t)i3*64+lane];
    u32 v4=hv[(size_t)i4*64+lane], v5=hv[(size_t)i5*64+lane];
    u32 v6=hv[(size_t)i6*64+lane], v7=hv[(size_t)i7*64+lane];
    ax+=bflo(v0)+bflo(v1)+bflo(v2)+bflo(v3)+bflo(v4)+bflo(v5)+bflo(v6)+bflo(v7);
    ay+=bfhi(v0)+bfhi(v1)+bfhi(v2)+bfhi(v3)+bfhi(v4)+bfhi(v5)+bfhi(v6)+bfhi(v7);
  }
  if(e+4<=e1){
    int i0=csr[e],i1=csr[e+1],i2=csr[e+2],i3=csr[e+3];
    u32 v0=hv[(size_t)i0*64+lane], v1=hv[(size_t)i1*64+lane];
    u32 v2=hv[(size_t)i2*64+lane], v3=hv[(size_t)i3*64+lane];
    ax+=bflo(v0)+bflo(v1)+bflo(v2)+bflo(v3);
    ay+=bfhi(v0)+bfhi(v1)+bfhi(v2)+bfhi(v3);
    e+=4;
  }
  if(e+2<=e1){
    int i0=csr[e],i1=csr[e+1];
    u32 v0=hv[(size_t)i0*64+lane], v1=hv[(size_t)i1*64+lane];
    ax+=bflo(v0)+bflo(v1);
    ay+=bfhi(v0)+bfhi(v1);
    e+=2;
  }
  if(e<e1){
    u32 v=hv[(size_t)csr[e]*64+lane];
    ax+=bflo(v); ay+=bfhi(v);
  }
  float di=dinv[node];
  float2 b=*(const float2*)&bias[lane*2];
  float ox=fmaf(di,ax,b.x), oy=fmaf(di,ay,b.y);
  ox=ox>0.f?ox:0.f; oy=oy>0.f?oy:0.f;
  u32 o=(u32)f2bf(ox) | ((u32)f2bf(oy)<<16);
  ((u32*)outp)[(size_t)node*64+lane]=o;
}

__global__ __launch_bounds__(128) void k_pool(const u16* __restrict__ h, const int* __restrict__ goff,
                                              const float* __restrict__ Wc, const float* __restrict__ bc,
                                              float* __restrict__ outp){
  __shared__ float lds[128];
  int g=blockIdx.x, d=threadIdx.x;
  int i0=goff[g], i1=goff[g+1];
  float acc=0.f;
  for(int i=i0;i<i1;++i) acc+=__uint_as_float(((u32)h[(size_t)i*128+d])<<16);
  int cnt=i1-i0;
  float p=(cnt>0)? acc/(float)cnt : 0.f;
  lds[d]=p;
  __syncthreads();
  if(d<NC){
    float s=bc[d];
    for(int k=0;k<128;++k) s=fmaf(lds[k], Wc[k*NC+d], s);
    outp[g*NC+d]=s;
  }
}

extern "C" void kernel_launch(void* const* d_in, const int* in_sizes, int n_in,
                              void* d_out, int out_size, void* d_ws, size_t ws_size,
                              hipStream_t stream){
  const float* x   =(const float*)d_in[0];
  const int* esrc  =(const int*)d_in[1];
  const int* edst  =(const int*)d_in[2];
  const int* batch =(const int*)d_in[3];
  const float* W0=(const float*)d_in[4];
  const float* W1=(const float*)d_in[6];
  const float* W2=(const float*)d_in[8];
  const float* b0=(const float*)d_in[5];
  const float* b1=(const float*)d_in[7];
  const float* b2=(const float*)d_in[9];
  const float* Wc=(const float*)d_in[10];
  const float* bc=(const float*)d_in[11];
  float* out=(float*)d_out;

  char* base=(char*)d_ws; size_t off=0;
  auto alloc=[&](size_t bytes)->void*{ off=(off+255)&~(size_t)255; void* p=base+off; off+=bytes; return p; };
  int*   cnt  =(int*)  alloc((size_t)NN*4);          // contiguous zero region start
  int*   gcnt =(int*)  alloc(NG*4);
  int*   cur  =(int*)  alloc(NBK*4);                 // contiguous zero region end
  int*   offs =(int*)  alloc((size_t)(NN+1)*4);
  int*   pos  =(int*)  alloc((size_t)NN*4);
  int*   bsum =(int*)  alloc(128*4);
  int*   bscan=(int*)  alloc(128*4);
  int*   goff =(int*)  alloc((NG+1)*4);
  float* dinv =(float*)alloc((size_t)NN*4);
  int*   csr  =(int*)  alloc((size_t)NE*4);
  uint2* pairs=(uint2*)alloc((size_t)NBK*BKCAP*8);
  u16*   WT   =(u16*)  alloc((size_t)3*DF*DF*2);
  u16*   bufA =(u16*)  alloc((size_t)NN*DF*2);
  u16*   bufB =(u16*)  alloc((size_t)NN*DF*2);
  (void)ws_size; (void)in_sizes; (void)n_in; (void)out_size;

  const int NB_N=(NN+255)/256, NB_S=(NN+1023)/1024;
  const int ZTOT=(int)((((char*)cur+(size_t)NBK*4)-(char*)cnt)/4);

  hipLaunchKernelGGL(k_zero,  dim3((ZTOT+255)/256), dim3(256), 0, stream, cnt, ZTOT);
  hipLaunchKernelGGL(k_prepW, dim3(192), dim3(256), 0, stream, W0, W1, W2, WT);
  hipLaunchKernelGGL(k_part8, dim3((NE+PCH-1)/PCH), dim3(256), 0, stream, esrc, edst, cur, pairs, cnt, NE);
  hipLaunchKernelGGL(k_count, dim3(NB_N), dim3(256), 0, stream, batch, gcnt, NN);
  hipLaunchKernelGGL(k_scan1, dim3(NB_S), dim3(1024),0, stream, cnt, offs, bsum, NN);
  hipLaunchKernelGGL(k_scan2, dim3(1),    dim3(128), 0, stream, bsum, bscan, NB_S);
  hipLaunchKernelGGL(k_scan3, dim3(NB_S), dim3(1024),0, stream, cnt, offs, pos, bscan, dinv, NN);
  hipLaunchKernelGGL(k_gscan, dim3(1),    dim3(512), 0, stream, gcnt, goff, NG);
  hipLaunchKernelGGL(k_place, dim3(512),  dim3(256), 0, stream, pairs, cur, pos, csr);

  const int GB=(NN+127)/128;    // 782
  const int AB=(NN+3)/4;        // 25000

  k_gemm<true ><<<dim3(GB), dim3(256), 0, stream>>>((const void*)x,    WT,           dinv, bufA, NN);
  hipLaunchKernelGGL(k_agg,  dim3(AB), dim3(256), 0, stream, bufA, offs, csr, dinv, b0, bufB, NN);
  k_gemm<false><<<dim3(GB), dim3(256), 0, stream>>>((const void*)bufB, WT+DF*DF,     dinv, bufA, NN);
  hipLaunchKernelGGL(k_agg,  dim3(AB), dim3(256), 0, stream, bufA, offs, csr, dinv, b1, bufB, NN);
  k_gemm<false><<<dim3(GB), dim3(256), 0, stream>>>((const void*)bufB, WT+2*DF*DF,   dinv, bufA, NN);
  hipLaunchKernelGGL(k_agg,  dim3(AB), dim3(256), 0, stream, bufA, offs, csr, dinv, b2, bufB, NN);
  hipLaunchKernelGGL(k_pool, dim3(NG), dim3(128), 0, stream, bufB, goff, Wc, bc, out);
}

// Round 6
// 467.926 us; speedup vs baseline: 2.0160x; 1.1604x over previous
//
#include <hip/hip_runtime.h>

#define NN 100000
#define NE 1600000
#define DF 128
#define NG 512
#define NC 10
#define NBK 8
#define NPB 12500      // nodes per bucket (NN/NBK exact)
#define BKCAP 262144   // pairs capacity per bucket
#define PCH 4096       // edges per partition block

typedef unsigned short u16;
typedef unsigned int u32;
typedef __bf16 bf16_t;
typedef bf16_t bf16x8 __attribute__((ext_vector_type(8)));
typedef float f32x4 __attribute__((ext_vector_type(4)));

__device__ __forceinline__ u16 f2bf(float f){
  u32 x=__float_as_uint(f);
  u32 r=(x+0x7fffu+((x>>16)&1u))>>16;
  return (u16)r;
}
__device__ __forceinline__ float bflo(u32 u){ return __uint_as_float(u<<16); }
__device__ __forceinline__ float bfhi(u32 u){ return __uint_as_float(u&0xffff0000u); }

__global__ void k_zero(int* p, int n){ int i=blockIdx.x*256+threadIdx.x; if(i<n) p[i]=0; }

// goff[g] = lower_bound(batch, g) — batch is sorted; no atomics needed
__global__ void k_goff(const int* __restrict__ batch, int* __restrict__ goff){
  int g=blockIdx.x*256+threadIdx.x;
  if(g>NG) return;
  int lo=0, hi=NN;
  while(lo<hi){ int mid=(lo+hi)>>1; if(batch[mid]<g) lo=mid+1; else hi=mid; }
  goff[g]=lo;
}

// partition edges into 8 dst-range buckets; also produce per-node degree counts
__global__ __launch_bounds__(256) void k_part8(const int* __restrict__ esrc, const int* __restrict__ edst,
                                               int* __restrict__ cur, uint2* __restrict__ pairs,
                                               int* __restrict__ cnt, int n){
  __shared__ int hist[NBK], basev[NBK], lcur[NBK];
  int tid=threadIdx.x;
  int start=blockIdx.x*PCH;
  int end=min(start+PCH, n);
  if(tid<NBK) hist[tid]=0;
  __syncthreads();
  for(int i=start+tid;i<end;i+=256){
    int d=edst[i];
    atomicAdd(&cnt[d],1);
    atomicAdd(&hist[(u32)d/NPB],1);
  }
  __syncthreads();
  if(tid<NBK){ basev[tid]=atomicAdd(&cur[tid],hist[tid]); lcur[tid]=0; }
  __syncthreads();
  for(int i=start+tid;i<end;i+=256){
    int d=edst[i], s=esrc[i];
    int b=(u32)d/NPB;
    int p=atomicAdd(&lcur[b],1);
    pairs[(size_t)b*BKCAP + basev[b] + p]=make_uint2((u32)s,(u32)d);
  }
}

// XCD-pinned CSR build: bucket = blockIdx&7
__global__ __launch_bounds__(256) void k_place(const uint2* __restrict__ pairs, const int* __restrict__ cur,
                                               int* __restrict__ pos, int* __restrict__ csr){
  int b=blockIdx.x&7, bi=blockIdx.x>>3, nb=gridDim.x>>3;
  int cnt=cur[b];
  const uint2* P=pairs+(size_t)b*BKCAP;
  for(int i=bi*256+threadIdx.x;i<cnt;i+=nb*256){
    uint2 e=P[i];
    int p=atomicAdd(&pos[e.y],1);
    csr[p]=(int)e.x;
  }
}

__device__ __forceinline__ int block_scan_excl_dev(int v, int* total){
  __shared__ int wsum[33];
  int tid=threadIdx.x, lane=tid&63, wid=tid>>6, nw=(int)(blockDim.x>>6);
  int x=v;
  #pragma unroll
  for(int off=1; off<64; off<<=1){ int t=__shfl_up(x,off,64); if(lane>=off) x+=t; }
  if(lane==63) wsum[wid]=x;
  __syncthreads();
  if(tid==0){ int acc=0; for(int w=0;w<nw;++w){ int t=wsum[w]; wsum[w]=acc; acc+=t; } wsum[32]=acc; }
  __syncthreads();
  if(total) *total=wsum[32];
  return x - v + wsum[wid];
}

__global__ void k_scan1(const int* __restrict__ in, int* __restrict__ out, int* __restrict__ bsum, int n){
  int i=blockIdx.x*1024+threadIdx.x;
  int v=(i<n)? in[i] : 0;
  int total;
  int e=block_scan_excl_dev(v,&total);
  if(i<n) out[i]=e;
  if(threadIdx.x==0) bsum[blockIdx.x]=total;
}

__global__ void k_scan2(const int* __restrict__ bsum, int* __restrict__ bscan, int nb){
  int v=(threadIdx.x<(unsigned)nb)? bsum[threadIdx.x] : 0;
  int e=block_scan_excl_dev(v,nullptr);
  if(threadIdx.x<(unsigned)nb) bscan[threadIdx.x]=e;
}

__global__ void k_scan3(const int* __restrict__ cnt, int* __restrict__ offs, int* __restrict__ pos,
                        const int* __restrict__ bscan, float* __restrict__ dinv, int n){
  int i=blockIdx.x*1024+threadIdx.x;
  if(i<n){
    int o=offs[i]+bscan[blockIdx.x];
    offs[i]=o; pos[i]=o;
    dinv[i]=rsqrtf((float)cnt[i]+1.0f);
    if(i==n-1) offs[n]=o+cnt[i];
  }
}

// all three W fp32 [128][128] row-major -> WT bf16 [w][n][k]
__global__ void k_prepW(const float* __restrict__ W0, const float* __restrict__ W1,
                        const float* __restrict__ W2, u16* __restrict__ WT){
  int t=blockIdx.x*256+threadIdx.x;   // grid 192 -> 49152 = 3*16384
  int w=t>>14, r=t&16383;
  const float* W = (w==0)?W0:((w==1)?W1:W2);
  int k=r>>7, n=r&127;
  WT[(size_t)w*DF*DF + n*128+k]=f2bf(W[r]);
}

// out[row][c] = bf16( dinv[row] * sum_k A[row][k]*W[k][c] ), MFMA bf16
template<bool F32IN>
__global__ __launch_bounds__(256) void k_gemm(const void* __restrict__ Ap, const u16* __restrict__ WT,
                                              const float* __restrict__ dinv, u16* __restrict__ outp, int n){
  __shared__ u16 sA[128][136];   // row stride 272B -> 2-way bank alias (free)
  __shared__ u16 sW[128][136];   // W^T: sW[n][k]
  int tid=threadIdx.x;
  int row0=blockIdx.x*128;
  {
    const uint4* p=(const uint4*)WT;
    #pragma unroll
    for(int j=0;j<8;++j){
      int c=tid+j*256;
      int r=c>>4, c8=c&15;
      *(uint4*)&sW[r][c8*8]=p[c];
    }
  }
  if(F32IN){
    const float4* A4=(const float4*)Ap;
    #pragma unroll
    for(int j=0;j<16;++j){
      int c=tid+j*256;
      int r=c>>5, c4=c&31;
      int row=row0+r;
      float4 v = (row<n)? A4[(size_t)row*32+c4] : make_float4(0.f,0.f,0.f,0.f);
      u32 lo=(u32)f2bf(v.x) | ((u32)f2bf(v.y)<<16);
      u32 hi=(u32)f2bf(v.z) | ((u32)f2bf(v.w)<<16);
      uint2 q; q.x=lo; q.y=hi;
      *(uint2*)&sA[r][c4*4]=q;
    }
  } else {
    const uint4* A4=(const uint4*)Ap;
    #pragma unroll
    for(int j=0;j<8;++j){
      int c=tid+j*256;
      int r=c>>4, c8=c&15;
      int row=row0+r;
      uint4 v = (row<n)? A4[(size_t)row*16+c8] : make_uint4(0,0,0,0);
      *(uint4*)&sA[r][c8*8]=v;
    }
  }
  __syncthreads();
  int wv=tid>>6, lane=tid&63;
  int lr=lane&15, lk=lane>>4;
  f32x4 acc[2][8];
  #pragma unroll
  for(int mr=0;mr<2;++mr)
    #pragma unroll
    for(int nt=0;nt<8;++nt) acc[mr][nt]=(f32x4){0.f,0.f,0.f,0.f};
  #pragma unroll
  for(int kk=0;kk<4;++kk){
    bf16x8 a[2], b[8];
    #pragma unroll
    for(int mr=0;mr<2;++mr)
      a[mr]=*(const bf16x8*)&sA[wv*32+mr*16+lr][kk*32+lk*8];
    #pragma unroll
    for(int nt=0;nt<8;++nt)
      b[nt]=*(const bf16x8*)&sW[nt*16+lr][kk*32+lk*8];
    #pragma unroll
    for(int mr=0;mr<2;++mr)
      #pragma unroll
      for(int nt=0;nt<8;++nt)
        acc[mr][nt]=__builtin_amdgcn_mfma_f32_16x16x32_bf16(a[mr],b[nt],acc[mr][nt],0,0,0);
  }
  #pragma unroll
  for(int mr=0;mr<2;++mr){
    int rbase=row0+wv*32+mr*16+lk*4;
    #pragma unroll
    for(int r=0;r<4;++r){
      int row=rbase+r;
      if(row<n){
        float di=dinv[row];
        #pragma unroll
        for(int nt=0;nt<8;++nt)
          outp[(size_t)row*128+nt*16+lr]=f2bf(acc[mr][nt][r]*di);
      }
    }
  }
}

// out[i] = bf16( relu(dinv[i]*(h2[i] + sum_e h2[csr[e]]) + b) )
__global__ __launch_bounds__(256) void k_agg(const u16* __restrict__ h2, const int* __restrict__ offs,
                                             const int* __restrict__ csr, const float* __restrict__ dinv,
                                             const float* __restrict__ bias, u16* __restrict__ outp, int n){
  int wid=threadIdx.x>>6, lane=threadIdx.x&63;
  int node=blockIdx.x*4+wid;
  if(node>=n) return;
  const u32* hv=(const u32*)h2;
  u32 sv=hv[(size_t)node*64+lane];
  float ax=bflo(sv), ay=bfhi(sv);
  int e=offs[node], e1=offs[node+1];
  // 16-wide main loop: 16 independent gathers in flight
  for(; e+16<=e1; e+=16){
    int ii[16];
    #pragma unroll
    for(int j=0;j<16;++j) ii[j]=csr[e+j];
    u32 vv[16];
    #pragma unroll
    for(int j=0;j<16;++j) vv[j]=hv[(size_t)ii[j]*64+lane];
    #pragma unroll
    for(int j=0;j<16;++j){ ax+=bflo(vv[j]); ay+=bfhi(vv[j]); }
  }
  if(e+8<=e1){
    int ii[8];
    #pragma unroll
    for(int j=0;j<8;++j) ii[j]=csr[e+j];
    u32 vv[8];
    #pragma unroll
    for(int j=0;j<8;++j) vv[j]=hv[(size_t)ii[j]*64+lane];
    #pragma unroll
    for(int j=0;j<8;++j){ ax+=bflo(vv[j]); ay+=bfhi(vv[j]); }
    e+=8;
  }
  if(e+4<=e1){
    int i0=csr[e],i1=csr[e+1],i2=csr[e+2],i3=csr[e+3];
    u32 v0=hv[(size_t)i0*64+lane], v1=hv[(size_t)i1*64+lane];
    u32 v2=hv[(size_t)i2*64+lane], v3=hv[(size_t)i3*64+lane];
    ax+=bflo(v0)+bflo(v1)+bflo(v2)+bflo(v3);
    ay+=bfhi(v0)+bfhi(v1)+bfhi(v2)+bfhi(v3);
    e+=4;
  }
  if(e+2<=e1){
    int i0=csr[e],i1=csr[e+1];
    u32 v0=hv[(size_t)i0*64+lane], v1=hv[(size_t)i1*64+lane];
    ax+=bflo(v0)+bflo(v1);
    ay+=bfhi(v0)+bfhi(v1);
    e+=2;
  }
  if(e<e1){
    u32 v=hv[(size_t)csr[e]*64+lane];
    ax+=bflo(v); ay+=bfhi(v);
  }
  float di=dinv[node];
  float2 b=*(const float2*)&bias[lane*2];
  float ox=fmaf(di,ax,b.x), oy=fmaf(di,ay,b.y);
  ox=ox>0.f?ox:0.f; oy=oy>0.f?oy:0.f;
  u32 o=(u32)f2bf(ox) | ((u32)f2bf(oy)<<16);
  ((u32*)outp)[(size_t)node*64+lane]=o;
}

__global__ __launch_bounds__(128) void k_pool(const u16* __restrict__ h, const int* __restrict__ goff,
                                              const float* __restrict__ Wc, const float* __restrict__ bc,
                                              float* __restrict__ outp){
  __shared__ float lds[128];
  int g=blockIdx.x, d=threadIdx.x;
  int i0=goff[g], i1=goff[g+1];
  float acc=0.f;
  for(int i=i0;i<i1;++i) acc+=__uint_as_float(((u32)h[(size_t)i*128+d])<<16);
  int cnt=i1-i0;
  float p=(cnt>0)? acc/(float)cnt : 0.f;
  lds[d]=p;
  __syncthreads();
  if(d<NC){
    float s=bc[d];
    for(int k=0;k<128;++k) s=fmaf(lds[k], Wc[k*NC+d], s);
    outp[g*NC+d]=s;
  }
}

extern "C" void kernel_launch(void* const* d_in, const int* in_sizes, int n_in,
                              void* d_out, int out_size, void* d_ws, size_t ws_size,
                              hipStream_t stream){
  const float* x   =(const float*)d_in[0];
  const int* esrc  =(const int*)d_in[1];
  const int* edst  =(const int*)d_in[2];
  const int* batch =(const int*)d_in[3];
  const float* W0=(const float*)d_in[4];
  const float* b0=(const float*)d_in[5];
  const float* W1=(const float*)d_in[6];
  const float* b1=(const float*)d_in[7];
  const float* W2=(const float*)d_in[8];
  const float* b2=(const float*)d_in[9];
  const float* Wc=(const float*)d_in[10];
  const float* bc=(const float*)d_in[11];
  float* out=(float*)d_out;

  char* base=(char*)d_ws; size_t off=0;
  auto alloc=[&](size_t bytes)->void*{ off=(off+255)&~(size_t)255; void* p=base+off; off+=bytes; return p; };
  int*   cnt  =(int*)  alloc((size_t)NN*4);          // contiguous zero region start
  int*   cur  =(int*)  alloc(NBK*4);                 // contiguous zero region end
  int*   offs =(int*)  alloc((size_t)(NN+1)*4);
  int*   pos  =(int*)  alloc((size_t)NN*4);
  int*   bsum =(int*)  alloc(128*4);
  int*   bscan=(int*)  alloc(128*4);
  int*   goff =(int*)  alloc((NG+1)*4);
  float* dinv =(float*)alloc((size_t)NN*4);
  int*   csr  =(int*)  alloc((size_t)NE*4);
  uint2* pairs=(uint2*)alloc((size_t)NBK*BKCAP*8);
  u16*   WT   =(u16*)  alloc((size_t)3*DF*DF*2);
  u16*   bufA =(u16*)  alloc((size_t)NN*DF*2);
  u16*   bufB =(u16*)  alloc((size_t)NN*DF*2);
  (void)ws_size; (void)in_sizes; (void)n_in; (void)out_size;

  const int NB_S=(NN+1023)/1024;
  // IMPORTANT: derive zero length from pointers — the allocator pads to 256B,
  // so cur is NOT at cnt+NN; hardcoding NN+NBK left cur poisoned (R5 crash).
  const int ZTOT=(int)((((char*)cur+(size_t)NBK*4)-(char*)cnt)/4);

  hipLaunchKernelGGL(k_zero,  dim3((ZTOT+255)/256), dim3(256), 0, stream, cnt, ZTOT);
  hipLaunchKernelGGL(k_prepW, dim3(192), dim3(256), 0, stream, W0, W1, W2, WT);
  hipLaunchKernelGGL(k_goff,  dim3(3),   dim3(256), 0, stream, batch, goff);
  hipLaunchKernelGGL(k_part8, dim3((NE+PCH-1)/PCH), dim3(256), 0, stream, esrc, edst, cur, pairs, cnt, NE);
  hipLaunchKernelGGL(k_scan1, dim3(NB_S), dim3(1024),0, stream, cnt, offs, bsum, NN);
  hipLaunchKernelGGL(k_scan2, dim3(1),    dim3(128), 0, stream, bsum, bscan, NB_S);
  hipLaunchKernelGGL(k_scan3, dim3(NB_S), dim3(1024),0, stream, cnt, offs, pos, bscan, dinv, NN);
  hipLaunchKernelGGL(k_place, dim3(512),  dim3(256), 0, stream, pairs, cur, pos, csr);

  const int GB=(NN+127)/128;    // 782
  const int AB=(NN+3)/4;        // 25000

  k_gemm<true ><<<dim3(GB), dim3(256), 0, stream>>>((const void*)x,    WT,           dinv, bufA, NN);
  hipLaunchKernelGGL(k_agg,  dim3(AB), dim3(256), 0, stream, bufA, offs, csr, dinv, b0, bufB, NN);
  k_gemm<false><<<dim3(GB), dim3(256), 0, stream>>>((const void*)bufB, WT+DF*DF,     dinv, bufA, NN);
  hipLaunchKernelGGL(k_agg,  dim3(AB), dim3(256), 0, stream, bufA, offs, csr, dinv, b1, bufB, NN);
  k_gemm<false><<<dim3(GB), dim3(256), 0, stream>>>((const void*)bufB, WT+2*DF*DF,   dinv, bufA, NN);
  hipLaunchKernelGGL(k_agg,  dim3(AB), dim3(256), 0, stream, bufA, offs, csr, dinv, b2, bufB, NN);
  hipLaunchKernelGGL(k_pool, dim3(NG), dim3(128), 0, stream, bufB, goff, Wc, bc, out);
}

// Round 7
// 462.288 us; speedup vs baseline: 2.0406x; 1.0122x over previous
//
#include <hip/hip_runtime.h>

#define NN 100000
#define NE 1600000
#define DF 128
#define NG 512
#define NC 10
#define NBK 8
#define NPB 12500      // nodes per bucket (NN/NBK exact)
#define BKCAP 262144   // pairs capacity per bucket
#define PCH 4096       // edges per partition block

typedef unsigned short u16;
typedef unsigned int u32;
typedef __bf16 bf16_t;
typedef bf16_t bf16x8 __attribute__((ext_vector_type(8)));
typedef float f32x4 __attribute__((ext_vector_type(4)));

__device__ __forceinline__ u16 f2bf(float f){
  u32 x=__float_as_uint(f);
  u32 r=(x+0x7fffu+((x>>16)&1u))>>16;
  return (u16)r;
}
__device__ __forceinline__ float bflo(u32 u){ return __uint_as_float(u<<16); }
__device__ __forceinline__ float bfhi(u32 u){ return __uint_as_float(u&0xffff0000u); }

// fused setup: zero cnt..cur region, prep W->WT bf16, goff binary search
__global__ void k_setup(int* __restrict__ zp, int zn,
                        const float* __restrict__ W0, const float* __restrict__ W1,
                        const float* __restrict__ W2, u16* __restrict__ WT,
                        const int* __restrict__ batch, int* __restrict__ goff){
  int i=blockIdx.x*256+threadIdx.x;
  if(i<zn) zp[i]=0;
  if(i<3*DF*DF){
    int w=i>>14, r=i&16383;
    const float* W = (w==0)?W0:((w==1)?W1:W2);
    int k=r>>7, n=r&127;
    WT[(size_t)w*DF*DF + n*128+k]=f2bf(W[r]);
  }
  if(i<=NG){
    int lo=0, hi=NN;
    while(lo<hi){ int mid=(lo+hi)>>1; if(batch[mid]<i) lo=mid+1; else hi=mid; }
    goff[i]=lo;
  }
}

// partition edges into 8 dst-range buckets with LDS staging (line-coherent flush);
// also produce per-node degree counts
__global__ __launch_bounds__(256) void k_part8(const int* __restrict__ esrc, const int* __restrict__ edst,
                                               int* __restrict__ cur, uint2* __restrict__ pairs,
                                               int* __restrict__ cnt, int n){
  __shared__ int hist[NBK], basev[NBK], lscan[NBK], lcur[NBK];
  __shared__ uint2 stage[PCH];    // 32 KB
  int tid=threadIdx.x;
  int start=blockIdx.x*PCH;
  int end=min(start+PCH, n);
  if(tid<NBK) hist[tid]=0;
  __syncthreads();
  for(int i=start+tid;i<end;i+=256){
    int d=edst[i];
    atomicAdd(&cnt[d],1);
    atomicAdd(&hist[(u32)d/NPB],1);
  }
  __syncthreads();
  if(tid==0){
    int acc=0;
    #pragma unroll
    for(int b=0;b<NBK;++b){ lscan[b]=acc; acc+=hist[b]; }
  }
  if(tid<NBK){ basev[tid]=atomicAdd(&cur[tid],hist[tid]); lcur[tid]=0; }
  __syncthreads();
  // scatter into LDS grouped by bucket
  for(int i=start+tid;i<end;i+=256){
    int d=edst[i], s=esrc[i];
    int b=(u32)d/NPB;
    int p=lscan[b]+atomicAdd(&lcur[b],1);
    stage[p]=make_uint2((u32)s,(u32)d);
  }
  __syncthreads();
  // flush each bucket's contiguous LDS run to its contiguous global reservation
  #pragma unroll
  for(int b=0;b<NBK;++b){
    int c=hist[b], bs=lscan[b];
    uint2* dp=pairs+(size_t)b*BKCAP+basev[b];
    for(int i=tid;i<c;i+=256) dp[i]=stage[bs+i];
  }
}

// XCD-pinned CSR build: bucket = blockIdx&7
__global__ __launch_bounds__(256) void k_place(const uint2* __restrict__ pairs, const int* __restrict__ cur,
                                               int* __restrict__ pos, int* __restrict__ csr){
  int b=blockIdx.x&7, bi=blockIdx.x>>3, nb=gridDim.x>>3;
  int cnt=cur[b];
  const uint2* P=pairs+(size_t)b*BKCAP;
  for(int i=bi*256+threadIdx.x;i<cnt;i+=nb*256){
    uint2 e=P[i];
    int p=atomicAdd(&pos[e.y],1);
    csr[p]=(int)e.x;
  }
}

__device__ __forceinline__ int block_scan_excl_dev(int v, int* total){
  __shared__ int wsum[33];
  int tid=threadIdx.x, lane=tid&63, wid=tid>>6, nw=(int)(blockDim.x>>6);
  int x=v;
  #pragma unroll
  for(int off=1; off<64; off<<=1){ int t=__shfl_up(x,off,64); if(lane>=off) x+=t; }
  if(lane==63) wsum[wid]=x;
  __syncthreads();
  if(tid==0){ int acc=0; for(int w=0;w<nw;++w){ int t=wsum[w]; wsum[w]=acc; acc+=t; } wsum[32]=acc; }
  __syncthreads();
  if(total) *total=wsum[32];
  return x - v + wsum[wid];
}

__global__ void k_scan1(const int* __restrict__ in, int* __restrict__ out, int* __restrict__ bsum, int n){
  int i=blockIdx.x*1024+threadIdx.x;
  int v=(i<n)? in[i] : 0;
  int total;
  int e=block_scan_excl_dev(v,&total);
  if(i<n) out[i]=e;
  if(threadIdx.x==0) bsum[blockIdx.x]=total;
}

__global__ void k_scan2(const int* __restrict__ bsum, int* __restrict__ bscan, int nb){
  int v=(threadIdx.x<(unsigned)nb)? bsum[threadIdx.x] : 0;
  int e=block_scan_excl_dev(v,nullptr);
  if(threadIdx.x<(unsigned)nb) bscan[threadIdx.x]=e;
}

__global__ void k_scan3(const int* __restrict__ cnt, int* __restrict__ offs, int* __restrict__ pos,
                        const int* __restrict__ bscan, float* __restrict__ dinv, int n){
  int i=blockIdx.x*1024+threadIdx.x;
  if(i<n){
    int o=offs[i]+bscan[blockIdx.x];
    offs[i]=o; pos[i]=o;
    dinv[i]=rsqrtf((float)cnt[i]+1.0f);
    if(i==n-1) offs[n]=o+cnt[i];
  }
}

// out[row][c] = bf16( dinv[row] * sum_k A[row][k]*W[k][c] ), MFMA bf16
template<bool F32IN>
__global__ __launch_bounds__(256) void k_gemm(const void* __restrict__ Ap, const u16* __restrict__ WT,
                                              const float* __restrict__ dinv, u16* __restrict__ outp, int n){
  __shared__ u16 sA[128][136];   // row stride 272B -> 2-way bank alias (free)
  __shared__ u16 sW[128][136];   // W^T: sW[n][k]
  int tid=threadIdx.x;
  int row0=blockIdx.x*128;
  {
    const uint4* p=(const uint4*)WT;
    #pragma unroll
    for(int j=0;j<8;++j){
      int c=tid+j*256;
      int r=c>>4, c8=c&15;
      *(uint4*)&sW[r][c8*8]=p[c];
    }
  }
  if(F32IN){
    const float4* A4=(const float4*)Ap;
    #pragma unroll
    for(int j=0;j<16;++j){
      int c=tid+j*256;
      int r=c>>5, c4=c&31;
      int row=row0+r;
      float4 v = (row<n)? A4[(size_t)row*32+c4] : make_float4(0.f,0.f,0.f,0.f);
      u32 lo=(u32)f2bf(v.x) | ((u32)f2bf(v.y)<<16);
      u32 hi=(u32)f2bf(v.z) | ((u32)f2bf(v.w)<<16);
      uint2 q; q.x=lo; q.y=hi;
      *(uint2*)&sA[r][c4*4]=q;
    }
  } else {
    const uint4* A4=(const uint4*)Ap;
    #pragma unroll
    for(int j=0;j<8;++j){
      int c=tid+j*256;
      int r=c>>4, c8=c&15;
      int row=row0+r;
      uint4 v = (row<n)? A4[(size_t)row*16+c8] : make_uint4(0,0,0,0);
      *(uint4*)&sA[r][c8*8]=v;
    }
  }
  __syncthreads();
  int wv=tid>>6, lane=tid&63;
  int lr=lane&15, lk=lane>>4;
  f32x4 acc[2][8];
  #pragma unroll
  for(int mr=0;mr<2;++mr)
    #pragma unroll
    for(int nt=0;nt<8;++nt) acc[mr][nt]=(f32x4){0.f,0.f,0.f,0.f};
  #pragma unroll
  for(int kk=0;kk<4;++kk){
    bf16x8 a[2], b[8];
    #pragma unroll
    for(int mr=0;mr<2;++mr)
      a[mr]=*(const bf16x8*)&sA[wv*32+mr*16+lr][kk*32+lk*8];
    #pragma unroll
    for(int nt=0;nt<8;++nt)
      b[nt]=*(const bf16x8*)&sW[nt*16+lr][kk*32+lk*8];
    #pragma unroll
    for(int mr=0;mr<2;++mr)
      #pragma unroll
      for(int nt=0;nt<8;++nt)
        acc[mr][nt]=__builtin_amdgcn_mfma_f32_16x16x32_bf16(a[mr],b[nt],acc[mr][nt],0,0,0);
  }
  #pragma unroll
  for(int mr=0;mr<2;++mr){
    int rbase=row0+wv*32+mr*16+lk*4;
    #pragma unroll
    for(int r=0;r<4;++r){
      int row=rbase+r;
      if(row<n){
        float di=dinv[row];
        #pragma unroll
        for(int nt=0;nt<8;++nt)
          outp[(size_t)row*128+nt*16+lr]=f2bf(acc[mr][nt][r]*di);
      }
    }
  }
}

// out[i] = bf16( relu(dinv[i]*(h2[i] + sum_e h2[csr[e]]) + b) )
__global__ __launch_bounds__(256) void k_agg(const u16* __restrict__ h2, const int* __restrict__ offs,
                                             const int* __restrict__ csr, const float* __restrict__ dinv,
                                             const float* __restrict__ bias, u16* __restrict__ outp, int n){
  int wid=threadIdx.x>>6, lane=threadIdx.x&63;
  int node=blockIdx.x*4+wid;
  if(node>=n) return;
  const u32* hv=(const u32*)h2;
  u32 sv=hv[(size_t)node*64+lane];
  float ax=bflo(sv), ay=bfhi(sv);
  int e=offs[node], e1=offs[node+1];
  for(; e+16<=e1; e+=16){
    int ii[16];
    #pragma unroll
    for(int j=0;j<16;++j) ii[j]=csr[e+j];
    u32 vv[16];
    #pragma unroll
    for(int j=0;j<16;++j) vv[j]=hv[(size_t)ii[j]*64+lane];
    #pragma unroll
    for(int j=0;j<16;++j){ ax+=bflo(vv[j]); ay+=bfhi(vv[j]); }
  }
  if(e+8<=e1){
    int ii[8];
    #pragma unroll
    for(int j=0;j<8;++j) ii[j]=csr[e+j];
    u32 vv[8];
    #pragma unroll
    for(int j=0;j<8;++j) vv[j]=hv[(size_t)ii[j]*64+lane];
    #pragma unroll
    for(int j=0;j<8;++j){ ax+=bflo(vv[j]); ay+=bfhi(vv[j]); }
    e+=8;
  }
  if(e+4<=e1){
    int i0=csr[e],i1=csr[e+1],i2=csr[e+2],i3=csr[e+3];
    u32 v0=hv[(size_t)i0*64+lane], v1=hv[(size_t)i1*64+lane];
    u32 v2=hv[(size_t)i2*64+lane], v3=hv[(size_t)i3*64+lane];
    ax+=bflo(v0)+bflo(v1)+bflo(v2)+bflo(v3);
    ay+=bfhi(v0)+bfhi(v1)+bfhi(v2)+bfhi(v3);
    e+=4;
  }
  if(e+2<=e1){
    int i0=csr[e],i1=csr[e+1];
    u32 v0=hv[(size_t)i0*64+lane], v1=hv[(size_t)i1*64+lane];
    ax+=bflo(v0)+bflo(v1);
    ay+=bfhi(v0)+bfhi(v1);
    e+=2;
  }
  if(e<e1){
    u32 v=hv[(size_t)csr[e]*64+lane];
    ax+=bflo(v); ay+=bfhi(v);
  }
  float di=dinv[node];
  float2 b=*(const float2*)&bias[lane*2];
  float ox=fmaf(di,ax,b.x), oy=fmaf(di,ay,b.y);
  ox=ox>0.f?ox:0.f; oy=oy>0.f?oy:0.f;
  u32 o=(u32)f2bf(ox) | ((u32)f2bf(oy)<<16);
  ((u32*)outp)[(size_t)node*64+lane]=o;
}

__global__ __launch_bounds__(128) void k_pool(const u16* __restrict__ h, const int* __restrict__ goff,
                                              const float* __restrict__ Wc, const float* __restrict__ bc,
                                              float* __restrict__ outp){
  __shared__ float lds[128];
  int g=blockIdx.x, d=threadIdx.x;
  int i0=goff[g], i1=goff[g+1];
  float acc=0.f;
  for(int i=i0;i<i1;++i) acc+=__uint_as_float(((u32)h[(size_t)i*128+d])<<16);
  int cnt=i1-i0;
  float p=(cnt>0)? acc/(float)cnt : 0.f;
  lds[d]=p;
  __syncthreads();
  if(d<NC){
    float s=bc[d];
    for(int k=0;k<128;++k) s=fmaf(lds[k], Wc[k*NC+d], s);
    outp[g*NC+d]=s;
  }
}

extern "C" void kernel_launch(void* const* d_in, const int* in_sizes, int n_in,
                              void* d_out, int out_size, void* d_ws, size_t ws_size,
                              hipStream_t stream){
  const float* x   =(const float*)d_in[0];
  const int* esrc  =(const int*)d_in[1];
  const int* edst  =(const int*)d_in[2];
  const int* batch =(const int*)d_in[3];
  const float* W0=(const float*)d_in[4];
  const float* b0=(const float*)d_in[5];
  const float* W1=(const float*)d_in[6];
  const float* b1=(const float*)d_in[7];
  const float* W2=(const float*)d_in[8];
  const float* b2=(const float*)d_in[9];
  const float* Wc=(const float*)d_in[10];
  const float* bc=(const float*)d_in[11];
  float* out=(float*)d_out;

  char* base=(char*)d_ws; size_t off=0;
  auto alloc=[&](size_t bytes)->void*{ off=(off+255)&~(size_t)255; void* p=base+off; off+=bytes; return p; };
  int*   cnt  =(int*)  alloc((size_t)NN*4);          // contiguous zero region start
  int*   cur  =(int*)  alloc(NBK*4);                 // contiguous zero region end
  int*   offs =(int*)  alloc((size_t)(NN+1)*4);
  int*   pos  =(int*)  alloc((size_t)NN*4);
  int*   bsum =(int*)  alloc(128*4);
  int*   bscan=(int*)  alloc(128*4);
  int*   goff =(int*)  alloc((NG+1)*4);
  float* dinv =(float*)alloc((size_t)NN*4);
  int*   csr  =(int*)  alloc((size_t)NE*4);
  uint2* pairs=(uint2*)alloc((size_t)NBK*BKCAP*8);
  u16*   WT   =(u16*)  alloc((size_t)3*DF*DF*2);
  u16*   bufA =(u16*)  alloc((size_t)NN*DF*2);
  u16*   bufB =(u16*)  alloc((size_t)NN*DF*2);
  (void)ws_size; (void)in_sizes; (void)n_in; (void)out_size;

  const int NB_S=(NN+1023)/1024;
  // derive zero length from pointers — allocator pads to 256B (R5 lesson)
  const int ZTOT=(int)((((char*)cur+(size_t)NBK*4)-(char*)cnt)/4);

  hipLaunchKernelGGL(k_setup, dim3((ZTOT+255)/256), dim3(256), 0, stream,
                     cnt, ZTOT, W0, W1, W2, WT, batch, goff);
  hipLaunchKernelGGL(k_part8, dim3((NE+PCH-1)/PCH), dim3(256), 0, stream, esrc, edst, cur, pairs, cnt, NE);
  hipLaunchKernelGGL(k_scan1, dim3(NB_S), dim3(1024),0, stream, cnt, offs, bsum, NN);
  hipLaunchKernelGGL(k_scan2, dim3(1),    dim3(128), 0, stream, bsum, bscan, NB_S);
  hipLaunchKernelGGL(k_scan3, dim3(NB_S), dim3(1024),0, stream, cnt, offs, pos, bscan, dinv, NN);
  hipLaunchKernelGGL(k_place, dim3(512),  dim3(256), 0, stream, pairs, cur, pos, csr);

  const int GB=(NN+127)/128;    // 782
  const int AB=(NN+3)/4;        // 25000

  k_gemm<true ><<<dim3(GB), dim3(256), 0, stream>>>((const void*)x,    WT,           dinv, bufA, NN);
  hipLaunchKernelGGL(k_agg,  dim3(AB), dim3(256), 0, stream, bufA, offs, csr, dinv, b0, bufB, NN);
  k_gemm<false><<<dim3(GB), dim3(256), 0, stream>>>((const void*)bufB, WT+DF*DF,     dinv, bufA, NN);
  hipLaunchKernelGGL(k_agg,  dim3(AB), dim3(256), 0, stream, bufA, offs, csr, dinv, b1, bufB, NN);
  k_gemm<false><<<dim3(GB), dim3(256), 0, stream>>>((const void*)bufB, WT+2*DF*DF,   dinv, bufA, NN);
  hipLaunchKernelGGL(k_agg,  dim3(AB), dim3(256), 0, stream, bufA, offs, csr, dinv, b2, bufB, NN);
  hipLaunchKernelGGL(k_pool, dim3(NG), dim3(128), 0, stream, bufB, goff, Wc, bc, out);
}

// Round 8
// 357.246 us; speedup vs baseline: 2.6406x; 1.2940x over previous
//
#include <hip/hip_runtime.h>

#define NN 100000
#define NE 1600000
#define DF 128
#define NG 512
#define NC 10
#define NBK 256
#define NPBN 391       // nodes per bucket = ceil(NN/NBK); last bucket has 295
#define BKCAP 8192     // pairs capacity per bucket (mean 6250, sigma ~79)
#define PCH 4096       // edges per partition block

typedef unsigned short u16;
typedef unsigned int u32;
typedef __bf16 bf16_t;
typedef bf16_t bf16x8 __attribute__((ext_vector_type(8)));
typedef float f32x4 __attribute__((ext_vector_type(4)));

__device__ __forceinline__ u16 f2bf(float f){
  u32 x=__float_as_uint(f);
  u32 r=(x+0x7fffu+((x>>16)&1u))>>16;
  return (u16)r;
}
__device__ __forceinline__ float bflo(u32 u){ return __uint_as_float(u<<16); }
__device__ __forceinline__ float bfhi(u32 u){ return __uint_as_float(u&0xffff0000u); }

// fused setup: zero cur[NBK], prep W->WT bf16, goff binary search
__global__ void k_setup(int* __restrict__ cur,
                        const float* __restrict__ W0, const float* __restrict__ W1,
                        const float* __restrict__ W2, u16* __restrict__ WT,
                        const int* __restrict__ batch, int* __restrict__ goff){
  int i=blockIdx.x*256+threadIdx.x;
  if(i<NBK) cur[i]=0;
  if(i<3*DF*DF){
    int w=i>>14, r=i&16383;
    const float* W = (w==0)?W0:((w==1)?W1:W2);
    int k=r>>7, n=r&127;
    WT[(size_t)w*DF*DF + n*128+k]=f2bf(W[r]);
  }
  if(i<=NG){
    int lo=0, hi=NN;
    while(lo<hi){ int mid=(lo+hi)>>1; if(batch[mid]<i) lo=mid+1; else hi=mid; }
    goff[i]=lo;
  }
}

// partition edges into 256 dst-range buckets; NO per-edge global atomics
__global__ __launch_bounds__(256) void k_part(const int* __restrict__ esrc, const int* __restrict__ edst,
                                              int* __restrict__ cur, uint2* __restrict__ pairs, int n){
  __shared__ int hist[NBK], basev[NBK], lscan[NBK], lcur[NBK];
  __shared__ uint2 stage[PCH];   // 32 KB
  int tid=threadIdx.x;
  int start=blockIdx.x*PCH, end=min(start+PCH,n);
  if(tid<NBK) hist[tid]=0;
  __syncthreads();
  for(int i=start+tid;i<end;i+=256) atomicAdd(&hist[(u32)edst[i]/NPBN],1);
  __syncthreads();
  // exclusive scan of hist[256] by wave 0 (4 chunks of 64)
  if(tid<64){
    int carry=0;
    #pragma unroll
    for(int c=0;c<NBK;c+=64){
      int v=hist[c+tid], x=v;
      #pragma unroll
      for(int off=1;off<64;off<<=1){ int t=__shfl_up(x,off,64); if(tid>=off) x+=t; }
      lscan[c+tid]=x-v+carry;
      carry+=__shfl(x,63,64);
    }
  }
  __syncthreads();
  if(tid<NBK){ basev[tid]=atomicAdd(&cur[tid],hist[tid]); lcur[tid]=0; }
  __syncthreads();
  // scatter into LDS grouped by bucket
  for(int i=start+tid;i<end;i+=256){
    int d=edst[i], s=esrc[i];
    int b=(u32)d/NPBN;
    int p=lscan[b]+atomicAdd(&lcur[b],1);
    stage[p]=make_uint2((u32)s,(u32)d);
  }
  __syncthreads();
  // flush: consecutive i within a bucket run -> consecutive dest (coalesced runs)
  int ntot=end-start;
  for(int i=tid;i<ntot;i+=256){
    uint2 e=stage[i];
    int b=(u32)e.y/NPBN;
    pairs[(size_t)b*BKCAP + basev[b] + (i - lscan[b])]=e;
  }
}

// one block per bucket: local histogram -> offs/dinv -> place csr (L2-local window)
__global__ __launch_bounds__(256) void k_bucket(const uint2* __restrict__ pairs, const int* __restrict__ cur,
                                                int* __restrict__ offs, float* __restrict__ dinv,
                                                int* __restrict__ csr){
  __shared__ int hist[NPBN], lsc[NPBN], curL[NBK];
  __shared__ int sbase[2];
  int b=blockIdx.x, tid=threadIdx.x;
  if(tid<NBK) curL[tid]=cur[tid];
  for(int j=tid;j<NPBN;j+=256) hist[j]=0;
  __syncthreads();
  // csr base = prefix sum of curL[<b]
  if(tid<64){
    int acc=0;
    #pragma unroll
    for(int c=0;c<NBK;c+=64){
      int v=(c+tid<b)? curL[c+tid] : 0;
      #pragma unroll
      for(int off=32;off;off>>=1) v+=__shfl_xor(v,off,64);
      acc+=v;
    }
    if(tid==0){ sbase[0]=acc; sbase[1]=curL[b]; }
  }
  __syncthreads();
  int base=sbase[0], count=sbase[1];
  int node0=b*NPBN;
  int nnode=min(NPBN, NN-node0);
  const uint2* P=pairs+(size_t)b*BKCAP;
  for(int i=tid;i<count;i+=256) atomicAdd(&hist[P[i].y-node0],1);
  __syncthreads();
  // exclusive scan of hist[391] by wave 0 (7 chunks)
  if(tid<64){
    int carry=0;
    #pragma unroll
    for(int c=0;c<448;c+=64){
      int idx=c+tid;
      int v=(idx<NPBN)? hist[idx] : 0, x=v;
      #pragma unroll
      for(int off=1;off<64;off<<=1){ int t=__shfl_up(x,off,64); if(tid>=off) x+=t; }
      if(idx<NPBN) lsc[idx]=x-v+carry;
      carry+=__shfl(x,63,64);
    }
  }
  __syncthreads();
  for(int j=tid;j<nnode;j+=256){
    offs[node0+j]=base+lsc[j];
    dinv[node0+j]=rsqrtf((float)hist[j]+1.0f);
  }
  if(b==NBK-1 && tid==0) offs[NN]=base+count;
  __syncthreads();
  for(int j=tid;j<nnode;j+=256) hist[j]=lsc[j];   // reuse hist as cursor
  __syncthreads();
  for(int i=tid;i<count;i+=256){
    uint2 e=P[i];
    int p=atomicAdd(&hist[e.y-node0],1);
    csr[base+p]=(int)e.x;
  }
}

// out[row][c] = bf16( dinv[row] * sum_k A[row][k]*W[k][c] ), MFMA bf16
template<bool F32IN>
__global__ __launch_bounds__(256) void k_gemm(const void* __restrict__ Ap, const u16* __restrict__ WT,
                                              const float* __restrict__ dinv, u16* __restrict__ outp, int n){
  __shared__ u16 sA[128][136];
  __shared__ u16 sW[128][136];
  int tid=threadIdx.x;
  int row0=blockIdx.x*128;
  {
    const uint4* p=(const uint4*)WT;
    #pragma unroll
    for(int j=0;j<8;++j){
      int c=tid+j*256;
      int r=c>>4, c8=c&15;
      *(uint4*)&sW[r][c8*8]=p[c];
    }
  }
  if(F32IN){
    const float4* A4=(const float4*)Ap;
    #pragma unroll
    for(int j=0;j<16;++j){
      int c=tid+j*256;
      int r=c>>5, c4=c&31;
      int row=row0+r;
      float4 v = (row<n)? A4[(size_t)row*32+c4] : make_float4(0.f,0.f,0.f,0.f);
      u32 lo=(u32)f2bf(v.x) | ((u32)f2bf(v.y)<<16);
      u32 hi=(u32)f2bf(v.z) | ((u32)f2bf(v.w)<<16);
      uint2 q; q.x=lo; q.y=hi;
      *(uint2*)&sA[r][c4*4]=q;
    }
  } else {
    const uint4* A4=(const uint4*)Ap;
    #pragma unroll
    for(int j=0;j<8;++j){
      int c=tid+j*256;
      int r=c>>4, c8=c&15;
      int row=row0+r;
      uint4 v = (row<n)? A4[(size_t)row*16+c8] : make_uint4(0,0,0,0);
      *(uint4*)&sA[r][c8*8]=v;
    }
  }
  __syncthreads();
  int wv=tid>>6, lane=tid&63;
  int lr=lane&15, lk=lane>>4;
  f32x4 acc[2][8];
  #pragma unroll
  for(int mr=0;mr<2;++mr)
    #pragma unroll
    for(int nt=0;nt<8;++nt) acc[mr][nt]=(f32x4){0.f,0.f,0.f,0.f};
  #pragma unroll
  for(int kk=0;kk<4;++kk){
    bf16x8 a[2], b[8];
    #pragma unroll
    for(int mr=0;mr<2;++mr)
      a[mr]=*(const bf16x8*)&sA[wv*32+mr*16+lr][kk*32+lk*8];
    #pragma unroll
    for(int nt=0;nt<8;++nt)
      b[nt]=*(const bf16x8*)&sW[nt*16+lr][kk*32+lk*8];
    #pragma unroll
    for(int mr=0;mr<2;++mr)
      #pragma unroll
      for(int nt=0;nt<8;++nt)
        acc[mr][nt]=__builtin_amdgcn_mfma_f32_16x16x32_bf16(a[mr],b[nt],acc[mr][nt],0,0,0);
  }
  #pragma unroll
  for(int mr=0;mr<2;++mr){
    int rbase=row0+wv*32+mr*16+lk*4;
    #pragma unroll
    for(int r=0;r<4;++r){
      int row=rbase+r;
      if(row<n){
        float di=dinv[row];
        #pragma unroll
        for(int nt=0;nt<8;++nt)
          outp[(size_t)row*128+nt*16+lr]=f2bf(acc[mr][nt][r]*di);
      }
    }
  }
}

// out[i] = bf16( relu(dinv[i]*(h2[i] + sum_e h2[csr[e]]) + b) )
__global__ __launch_bounds__(256) void k_agg(const u16* __restrict__ h2, const int* __restrict__ offs,
                                             const int* __restrict__ csr, const float* __restrict__ dinv,
                                             const float* __restrict__ bias, u16* __restrict__ outp, int n){
  int wid=threadIdx.x>>6, lane=threadIdx.x&63;
  int node=blockIdx.x*4+wid;
  if(node>=n) return;
  const u32* hv=(const u32*)h2;
  u32 sv=hv[(size_t)node*64+lane];
  float ax=bflo(sv), ay=bfhi(sv);
  int e=offs[node], e1=offs[node+1];
  for(; e+16<=e1; e+=16){
    int ii[16];
    #pragma unroll
    for(int j=0;j<16;++j) ii[j]=csr[e+j];
    u32 vv[16];
    #pragma unroll
    for(int j=0;j<16;++j) vv[j]=hv[(size_t)ii[j]*64+lane];
    #pragma unroll
    for(int j=0;j<16;++j){ ax+=bflo(vv[j]); ay+=bfhi(vv[j]); }
  }
  if(e+8<=e1){
    int ii[8];
    #pragma unroll
    for(int j=0;j<8;++j) ii[j]=csr[e+j];
    u32 vv[8];
    #pragma unroll
    for(int j=0;j<8;++j) vv[j]=hv[(size_t)ii[j]*64+lane];
    #pragma unroll
    for(int j=0;j<8;++j){ ax+=bflo(vv[j]); ay+=bfhi(vv[j]); }
    e+=8;
  }
  if(e+4<=e1){
    int i0=csr[e],i1=csr[e+1],i2=csr[e+2],i3=csr[e+3];
    u32 v0=hv[(size_t)i0*64+lane], v1=hv[(size_t)i1*64+lane];
    u32 v2=hv[(size_t)i2*64+lane], v3=hv[(size_t)i3*64+lane];
    ax+=bflo(v0)+bflo(v1)+bflo(v2)+bflo(v3);
    ay+=bfhi(v0)+bfhi(v1)+bfhi(v2)+bfhi(v3);
    e+=4;
  }
  if(e+2<=e1){
    int i0=csr[e],i1=csr[e+1];
    u32 v0=hv[(size_t)i0*64+lane], v1=hv[(size_t)i1*64+lane];
    ax+=bflo(v0)+bflo(v1);
    ay+=bfhi(v0)+bfhi(v1);
    e+=2;
  }
  if(e<e1){
    u32 v=hv[(size_t)csr[e]*64+lane];
    ax+=bflo(v); ay+=bfhi(v);
  }
  float di=dinv[node];
  float2 b=*(const float2*)&bias[lane*2];
  float ox=fmaf(di,ax,b.x), oy=fmaf(di,ay,b.y);
  ox=ox>0.f?ox:0.f; oy=oy>0.f?oy:0.f;
  u32 o=(u32)f2bf(ox) | ((u32)f2bf(oy)<<16);
  ((u32*)outp)[(size_t)node*64+lane]=o;
}

__global__ __launch_bounds__(128) void k_pool(const u16* __restrict__ h, const int* __restrict__ goff,
                                              const float* __restrict__ Wc, const float* __restrict__ bc,
                                              float* __restrict__ outp){
  __shared__ float lds[128];
  int g=blockIdx.x, d=threadIdx.x;
  int i0=goff[g], i1=goff[g+1];
  float acc=0.f;
  for(int i=i0;i<i1;++i) acc+=__uint_as_float(((u32)h[(size_t)i*128+d])<<16);
  int cnt=i1-i0;
  float p=(cnt>0)? acc/(float)cnt : 0.f;
  lds[d]=p;
  __syncthreads();
  if(d<NC){
    float s=bc[d];
    for(int k=0;k<128;++k) s=fmaf(lds[k], Wc[k*NC+d], s);
    outp[g*NC+d]=s;
  }
}

extern "C" void kernel_launch(void* const* d_in, const int* in_sizes, int n_in,
                              void* d_out, int out_size, void* d_ws, size_t ws_size,
                              hipStream_t stream){
  const float* x   =(const float*)d_in[0];
  const int* esrc  =(const int*)d_in[1];
  const int* edst  =(const int*)d_in[2];
  const int* batch =(const int*)d_in[3];
  const float* W0=(const float*)d_in[4];
  const float* b0=(const float*)d_in[5];
  const float* W1=(const float*)d_in[6];
  const float* b1=(const float*)d_in[7];
  const float* W2=(const float*)d_in[8];
  const float* b2=(const float*)d_in[9];
  const float* Wc=(const float*)d_in[10];
  const float* bc=(const float*)d_in[11];
  float* out=(float*)d_out;

  char* base=(char*)d_ws; size_t off=0;
  auto alloc=[&](size_t bytes)->void*{ off=(off+255)&~(size_t)255; void* p=base+off; off+=bytes; return p; };
  int*   cur  =(int*)  alloc(NBK*4);
  int*   offs =(int*)  alloc((size_t)(NN+1)*4);
  int*   goff =(int*)  alloc((NG+1)*4);
  float* dinv =(float*)alloc((size_t)NN*4);
  int*   csr  =(int*)  alloc((size_t)NE*4);
  uint2* pairs=(uint2*)alloc((size_t)NBK*BKCAP*8);
  u16*   WT   =(u16*)  alloc((size_t)3*DF*DF*2);
  u16*   bufA =(u16*)  alloc((size_t)NN*DF*2);
  u16*   bufB =(u16*)  alloc((size_t)NN*DF*2);
  (void)ws_size; (void)in_sizes; (void)n_in; (void)out_size;

  hipLaunchKernelGGL(k_setup,  dim3(192),  dim3(256), 0, stream, cur, W0, W1, W2, WT, batch, goff);
  hipLaunchKernelGGL(k_part,   dim3((NE+PCH-1)/PCH), dim3(256), 0, stream, esrc, edst, cur, pairs, NE);
  hipLaunchKernelGGL(k_bucket, dim3(NBK),  dim3(256), 0, stream, pairs, cur, offs, dinv, csr);

  const int GB=(NN+127)/128;    // 782
  const int AB=(NN+3)/4;        // 25000

  k_gemm<true ><<<dim3(GB), dim3(256), 0, stream>>>((const void*)x,    WT,           dinv, bufA, NN);
  hipLaunchKernelGGL(k_agg,  dim3(AB), dim3(256), 0, stream, bufA, offs, csr, dinv, b0, bufB, NN);
  k_gemm<false><<<dim3(GB), dim3(256), 0, stream>>>((const void*)bufB, WT+DF*DF,     dinv, bufA, NN);
  hipLaunchKernelGGL(k_agg,  dim3(AB), dim3(256), 0, stream, bufA, offs, csr, dinv, b1, bufB, NN);
  k_gemm<false><<<dim3(GB), dim3(256), 0, stream>>>((const void*)bufB, WT+2*DF*DF,   dinv, bufA, NN);
  hipLaunchKernelGGL(k_agg,  dim3(AB), dim3(256), 0, stream, bufA, offs, csr, dinv, b2, bufB, NN);
  hipLaunchKernelGGL(k_pool, dim3(NG), dim3(128), 0, stream, bufB, goff, Wc, bc, out);
}

// Round 9
// 306.858 us; speedup vs baseline: 3.0742x; 1.1642x over previous
//
#include <hip/hip_runtime.h>

#define NN 100000
#define NE 1600000
#define DF 128
#define NG 512
#define NC 10
#define NBK 256
#define NPBN 391       // nodes per bucket = ceil(NN/NBK); last bucket has 295
#define BKCAP 8192     // pairs capacity per bucket (mean 6250, sigma ~79)
#define PCH 4096       // edges per partition block

typedef unsigned short u16;
typedef unsigned int u32;
typedef __bf16 bf16_t;
typedef bf16_t bf16x8 __attribute__((ext_vector_type(8)));
typedef float f32x4 __attribute__((ext_vector_type(4)));

__device__ __forceinline__ u16 f2bf(float f){
  u32 x=__float_as_uint(f);
  u32 r=(x+0x7fffu+((x>>16)&1u))>>16;
  return (u16)r;
}
__device__ __forceinline__ float bflo(u32 u){ return __uint_as_float(u<<16); }
__device__ __forceinline__ float bfhi(u32 u){ return __uint_as_float(u&0xffff0000u); }

// fused setup: zero cur[NBK], prep W->WT bf16, goff binary search
__global__ void k_setup(int* __restrict__ cur,
                        const float* __restrict__ W0, const float* __restrict__ W1,
                        const float* __restrict__ W2, u16* __restrict__ WT,
                        const int* __restrict__ batch, int* __restrict__ goff){
  int i=blockIdx.x*256+threadIdx.x;
  if(i<NBK) cur[i]=0;
  if(i<3*DF*DF){
    int w=i>>14, r=i&16383;
    const float* W = (w==0)?W0:((w==1)?W1:W2);
    int k=r>>7, n=r&127;
    WT[(size_t)w*DF*DF + n*128+k]=f2bf(W[r]);
  }
  if(i<=NG){
    int lo=0, hi=NN;
    while(lo<hi){ int mid=(lo+hi)>>1; if(batch[mid]<i) lo=mid+1; else hi=mid; }
    goff[i]=lo;
  }
}

// partition edges into 256 dst-range buckets; NO per-edge global atomics
__global__ __launch_bounds__(256) void k_part(const int* __restrict__ esrc, const int* __restrict__ edst,
                                              int* __restrict__ cur, uint2* __restrict__ pairs, int n){
  __shared__ int hist[NBK], basev[NBK], lscan[NBK], lcur[NBK];
  __shared__ uint2 stage[PCH];   // 32 KB
  int tid=threadIdx.x;
  int start=blockIdx.x*PCH, end=min(start+PCH,n);
  if(tid<NBK) hist[tid]=0;
  __syncthreads();
  for(int i=start+tid;i<end;i+=256) atomicAdd(&hist[(u32)edst[i]/NPBN],1);
  __syncthreads();
  // exclusive scan of hist[256] by wave 0 (4 chunks of 64)
  if(tid<64){
    int carry=0;
    #pragma unroll
    for(int c=0;c<NBK;c+=64){
      int v=hist[c+tid], x=v;
      #pragma unroll
      for(int off=1;off<64;off<<=1){ int t=__shfl_up(x,off,64); if(tid>=off) x+=t; }
      lscan[c+tid]=x-v+carry;
      carry+=__shfl(x,63,64);
    }
  }
  __syncthreads();
  if(tid<NBK){ basev[tid]=atomicAdd(&cur[tid],hist[tid]); lcur[tid]=0; }
  __syncthreads();
  // scatter into LDS grouped by bucket
  for(int i=start+tid;i<end;i+=256){
    int d=edst[i], s=esrc[i];
    int b=(u32)d/NPBN;
    int p=lscan[b]+atomicAdd(&lcur[b],1);
    stage[p]=make_uint2((u32)s,(u32)d);
  }
  __syncthreads();
  // flush: consecutive i within a bucket run -> consecutive dest (coalesced runs)
  int ntot=end-start;
  for(int i=tid;i<ntot;i+=256){
    uint2 e=stage[i];
    int b=(u32)e.y/NPBN;
    pairs[(size_t)b*BKCAP + basev[b] + (i - lscan[b])]=e;
  }
}

// one block per bucket: local histogram -> offs/dinv -> place csr (L2-local window)
__global__ __launch_bounds__(256) void k_bucket(const uint2* __restrict__ pairs, const int* __restrict__ cur,
                                                int* __restrict__ offs, float* __restrict__ dinv,
                                                int* __restrict__ csr){
  __shared__ int hist[NPBN], lsc[NPBN], curL[NBK];
  __shared__ int sbase[2];
  int b=blockIdx.x, tid=threadIdx.x;
  if(tid<NBK) curL[tid]=cur[tid];
  for(int j=tid;j<NPBN;j+=256) hist[j]=0;
  __syncthreads();
  // csr base = prefix sum of curL[<b]
  if(tid<64){
    int acc=0;
    #pragma unroll
    for(int c=0;c<NBK;c+=64){
      int v=(c+tid<b)? curL[c+tid] : 0;
      #pragma unroll
      for(int off=32;off;off>>=1) v+=__shfl_xor(v,off,64);
      acc+=v;
    }
    if(tid==0){ sbase[0]=acc; sbase[1]=curL[b]; }
  }
  __syncthreads();
  int base=sbase[0], count=sbase[1];
  int node0=b*NPBN;
  int nnode=min(NPBN, NN-node0);
  const uint2* P=pairs+(size_t)b*BKCAP;
  for(int i=tid;i<count;i+=256) atomicAdd(&hist[P[i].y-node0],1);
  __syncthreads();
  // exclusive scan of hist[391] by wave 0 (7 chunks)
  if(tid<64){
    int carry=0;
    #pragma unroll
    for(int c=0;c<448;c+=64){
      int idx=c+tid;
      int v=(idx<NPBN)? hist[idx] : 0, x=v;
      #pragma unroll
      for(int off=1;off<64;off<<=1){ int t=__shfl_up(x,off,64); if(tid>=off) x+=t; }
      if(idx<NPBN) lsc[idx]=x-v+carry;
      carry+=__shfl(x,63,64);
    }
  }
  __syncthreads();
  for(int j=tid;j<nnode;j+=256){
    offs[node0+j]=base+lsc[j];
    dinv[node0+j]=rsqrtf((float)hist[j]+1.0f);
  }
  if(b==NBK-1 && tid==0) offs[NN]=base+count;
  __syncthreads();
  for(int j=tid;j<nnode;j+=256) hist[j]=lsc[j];   // reuse hist as cursor
  __syncthreads();
  for(int i=tid;i<count;i+=256){
    uint2 e=P[i];
    int p=atomicAdd(&hist[e.y-node0],1);
    csr[base+p]=(int)e.x;
  }
}

// out[row][c] = bf16( dinv[row] * sum_k A[row][k]*W[k][c] ), MFMA bf16
template<bool F32IN>
__global__ __launch_bounds__(256) void k_gemm(const void* __restrict__ Ap, const u16* __restrict__ WT,
                                              const float* __restrict__ dinv, u16* __restrict__ outp, int n){
  __shared__ u16 sA[128][136];
  __shared__ u16 sW[128][136];
  int tid=threadIdx.x;
  int row0=blockIdx.x*128;
  {
    const uint4* p=(const uint4*)WT;
    #pragma unroll
    for(int j=0;j<8;++j){
      int c=tid+j*256;
      int r=c>>4, c8=c&15;
      *(uint4*)&sW[r][c8*8]=p[c];
    }
  }
  if(F32IN){
    const float4* A4=(const float4*)Ap;
    #pragma unroll
    for(int j=0;j<16;++j){
      int c=tid+j*256;
      int r=c>>5, c4=c&31;
      int row=row0+r;
      float4 v = (row<n)? A4[(size_t)row*32+c4] : make_float4(0.f,0.f,0.f,0.f);
      u32 lo=(u32)f2bf(v.x) | ((u32)f2bf(v.y)<<16);
      u32 hi=(u32)f2bf(v.z) | ((u32)f2bf(v.w)<<16);
      uint2 q; q.x=lo; q.y=hi;
      *(uint2*)&sA[r][c4*4]=q;
    }
  } else {
    const uint4* A4=(const uint4*)Ap;
    #pragma unroll
    for(int j=0;j<8;++j){
      int c=tid+j*256;
      int r=c>>4, c8=c&15;
      int row=row0+r;
      uint4 v = (row<n)? A4[(size_t)row*16+c8] : make_uint4(0,0,0,0);
      *(uint4*)&sA[r][c8*8]=v;
    }
  }
  __syncthreads();
  int wv=tid>>6, lane=tid&63;
  int lr=lane&15, lk=lane>>4;
  f32x4 acc[2][8];
  #pragma unroll
  for(int mr=0;mr<2;++mr)
    #pragma unroll
    for(int nt=0;nt<8;++nt) acc[mr][nt]=(f32x4){0.f,0.f,0.f,0.f};
  #pragma unroll
  for(int kk=0;kk<4;++kk){
    bf16x8 a[2], b[8];
    #pragma unroll
    for(int mr=0;mr<2;++mr)
      a[mr]=*(const bf16x8*)&sA[wv*32+mr*16+lr][kk*32+lk*8];
    #pragma unroll
    for(int nt=0;nt<8;++nt)
      b[nt]=*(const bf16x8*)&sW[nt*16+lr][kk*32+lk*8];
    #pragma unroll
    for(int mr=0;mr<2;++mr)
      #pragma unroll
      for(int nt=0;nt<8;++nt)
        acc[mr][nt]=__builtin_amdgcn_mfma_f32_16x16x32_bf16(a[mr],b[nt],acc[mr][nt],0,0,0);
  }
  #pragma unroll
  for(int mr=0;mr<2;++mr){
    int rbase=row0+wv*32+mr*16+lk*4;
    #pragma unroll
    for(int r=0;r<4;++r){
      int row=rbase+r;
      if(row<n){
        float di=dinv[row];
        #pragma unroll
        for(int nt=0;nt<8;++nt)
          outp[(size_t)row*128+nt*16+lr]=f2bf(acc[mr][nt][r]*di);
      }
    }
  }
}

// out[i] = bf16( relu(dinv[i]*(h2[i] + sum_e h2[csr[e]]) + b) )
__global__ __launch_bounds__(256) void k_agg(const u16* __restrict__ h2, const int* __restrict__ offs,
                                             const int* __restrict__ csr, const float* __restrict__ dinv,
                                             const float* __restrict__ bias, u16* __restrict__ outp, int n){
  int wid=threadIdx.x>>6, lane=threadIdx.x&63;
  int node=blockIdx.x*4+wid;
  if(node>=n) return;
  const u32* hv=(const u32*)h2;
  u32 sv=hv[(size_t)node*64+lane];
  float ax=bflo(sv), ay=bfhi(sv);
  int e=offs[node], e1=offs[node+1];
  for(; e+16<=e1; e+=16){
    int ii[16];
    #pragma unroll
    for(int j=0;j<16;++j) ii[j]=csr[e+j];
    u32 vv[16];
    #pragma unroll
    for(int j=0;j<16;++j) vv[j]=hv[(size_t)ii[j]*64+lane];
    #pragma unroll
    for(int j=0;j<16;++j){ ax+=bflo(vv[j]); ay+=bfhi(vv[j]); }
  }
  if(e+8<=e1){
    int ii[8];
    #pragma unroll
    for(int j=0;j<8;++j) ii[j]=csr[e+j];
    u32 vv[8];
    #pragma unroll
    for(int j=0;j<8;++j) vv[j]=hv[(size_t)ii[j]*64+lane];
    #pragma unroll
    for(int j=0;j<8;++j){ ax+=bflo(vv[j]); ay+=bfhi(vv[j]); }
    e+=8;
  }
  if(e+4<=e1){
    int i0=csr[e],i1=csr[e+1],i2=csr[e+2],i3=csr[e+3];
    u32 v0=hv[(size_t)i0*64+lane], v1=hv[(size_t)i1*64+lane];
    u32 v2=hv[(size_t)i2*64+lane], v3=hv[(size_t)i3*64+lane];
    ax+=bflo(v0)+bflo(v1)+bflo(v2)+bflo(v3);
    ay+=bfhi(v0)+bfhi(v1)+bfhi(v2)+bfhi(v3);
    e+=4;
  }
  if(e+2<=e1){
    int i0=csr[e],i1=csr[e+1];
    u32 v0=hv[(size_t)i0*64+lane], v1=hv[(size_t)i1*64+lane];
    ax+=bflo(v0)+bflo(v1);
    ay+=bfhi(v0)+bfhi(v1);
    e+=2;
  }
  if(e<e1){
    u32 v=hv[(size_t)csr[e]*64+lane];
    ax+=bflo(v); ay+=bfhi(v);
  }
  float di=dinv[node];
  float2 b=*(const float2*)&bias[lane*2];
  float ox=fmaf(di,ax,b.x), oy=fmaf(di,ay,b.y);
  ox=ox>0.f?ox:0.f; oy=oy>0.f?oy:0.f;
  u32 o=(u32)f2bf(ox) | ((u32)f2bf(oy)<<16);
  ((u32*)outp)[(size_t)node*64+lane]=o;
}

// 8-wave pooling: wave w strides rows, lane loads u32 (2 cols); LDS reduce + matvec
__global__ __launch_bounds__(512) void k_pool(const u16* __restrict__ h, const int* __restrict__ goff,
                                              const float* __restrict__ Wc, const float* __restrict__ bc,
                                              float* __restrict__ outp){
  __shared__ float part[8][128];
  __shared__ float pooled[128];
  int g=blockIdx.x;
  int tid=threadIdx.x, wid=tid>>6, lane=tid&63;
  int i0=goff[g], i1=goff[g+1];
  const u32* hv=(const u32*)h;
  float ax=0.f, ay=0.f;
  for(int i=i0+wid;i<i1;i+=8){
    u32 v=hv[(size_t)i*64+lane];
    ax+=bflo(v); ay+=bfhi(v);
  }
  part[wid][lane*2]=ax; part[wid][lane*2+1]=ay;
  __syncthreads();
  if(tid<128){
    float s=part[0][tid]+part[1][tid]+part[2][tid]+part[3][tid]
           +part[4][tid]+part[5][tid]+part[6][tid]+part[7][tid];
    int cnt=i1-i0;
    pooled[tid]=(cnt>0)? s/(float)cnt : 0.f;
  }
  __syncthreads();
  if(tid<NC){
    float s=bc[tid];
    #pragma unroll 16
    for(int k=0;k<128;++k) s=fmaf(pooled[k], Wc[k*NC+tid], s);
    outp[g*NC+tid]=s;
  }
}

extern "C" void kernel_launch(void* const* d_in, const int* in_sizes, int n_in,
                              void* d_out, int out_size, void* d_ws, size_t ws_size,
                              hipStream_t stream){
  const float* x   =(const float*)d_in[0];
  const int* esrc  =(const int*)d_in[1];
  const int* edst  =(const int*)d_in[2];
  const int* batch =(const int*)d_in[3];
  const float* W0=(const float*)d_in[4];
  const float* b0=(const float*)d_in[5];
  const float* W1=(const float*)d_in[6];
  const float* b1=(const float*)d_in[7];
  const float* W2=(const float*)d_in[8];
  const float* b2=(const float*)d_in[9];
  const float* Wc=(const float*)d_in[10];
  const float* bc=(const float*)d_in[11];
  float* out=(float*)d_out;

  char* base=(char*)d_ws; size_t off=0;
  auto alloc=[&](size_t bytes)->void*{ off=(off+255)&~(size_t)255; void* p=base+off; off+=bytes; return p; };
  int*   cur  =(int*)  alloc(NBK*4);
  int*   offs =(int*)  alloc((size_t)(NN+1)*4);
  int*   goff =(int*)  alloc((NG+1)*4);
  float* dinv =(float*)alloc((size_t)NN*4);
  int*   csr  =(int*)  alloc((size_t)NE*4);
  uint2* pairs=(uint2*)alloc((size_t)NBK*BKCAP*8);
  u16*   WT   =(u16*)  alloc((size_t)3*DF*DF*2);
  u16*   bufA =(u16*)  alloc((size_t)NN*DF*2);
  u16*   bufB =(u16*)  alloc((size_t)NN*DF*2);
  (void)ws_size; (void)in_sizes; (void)n_in; (void)out_size;

  hipLaunchKernelGGL(k_setup,  dim3(192),  dim3(256), 0, stream, cur, W0, W1, W2, WT, batch, goff);
  hipLaunchKernelGGL(k_part,   dim3((NE+PCH-1)/PCH), dim3(256), 0, stream, esrc, edst, cur, pairs, NE);
  hipLaunchKernelGGL(k_bucket, dim3(NBK),  dim3(256), 0, stream, pairs, cur, offs, dinv, csr);

  const int GB=(NN+127)/128;    // 782
  const int AB=(NN+3)/4;        // 25000

  k_gemm<true ><<<dim3(GB), dim3(256), 0, stream>>>((const void*)x,    WT,           dinv, bufA, NN);
  hipLaunchKernelGGL(k_agg,  dim3(AB), dim3(256), 0, stream, bufA, offs, csr, dinv, b0, bufB, NN);
  k_gemm<false><<<dim3(GB), dim3(256), 0, stream>>>((const void*)bufB, WT+DF*DF,     dinv, bufA, NN);
  hipLaunchKernelGGL(k_agg,  dim3(AB), dim3(256), 0, stream, bufA, offs, csr, dinv, b1, bufB, NN);
  k_gemm<false><<<dim3(GB), dim3(256), 0, stream>>>((const void*)bufB, WT+2*DF*DF,   dinv, bufA, NN);
  hipLaunchKernelGGL(k_agg,  dim3(AB), dim3(256), 0, stream, bufA, offs, csr, dinv, b2, bufB, NN);
  hipLaunchKernelGGL(k_pool, dim3(NG), dim3(512), 0, stream, bufB, goff, Wc, bc, out);
}